// Round 10
// baseline (1765.099 us; speedup 1.0000x reference)
//
#include <hip/hip_runtime.h>

#define NN 100000
#define EE 600000
#define FIN 39
#define HD 128
#define K1 256          // W1t layout K (k<128 = target half, k>=128 = source half)
#define NT32 (EE / 32)  // 18750 edge tiles of 32
#define NGRP (NN / 16)  // 6250 node groups of 16
#define LOSCALE 4096.0f
#define INV_LOSCALE (1.0f / 4096.0f)
#define SCB 98          // scan blocks per graph: 98*1024 >= NN

typedef _Float16 f16x8 __attribute__((ext_vector_type(8)));
typedef __attribute__((ext_vector_type(4))) float f32x4;

#define MFMA16(a, b, c) __builtin_amdgcn_mfma_f32_16x16x32_f16((a), (b), (c), 0, 0, 0)

__device__ __forceinline__ void split_hl(float x, unsigned short& hi, unsigned short& lo) {
    union { _Float16 h; unsigned short u; } a, b;
    a.h = (_Float16)x;
    float r = (x - (float)a.h) * LOSCALE;   // scaled residual stays fp16-normal
    b.h = (_Float16)r;
    hi = a.u; lo = b.u;
}

// LDS-only barrier: drains LDS ops (cross-wave staging visibility) but leaves VMEM
// loads in flight. __syncthreads() would emit s_waitcnt vmcnt(0) before s_barrier,
// force-draining the gather prefetch every phase (the R2..R6 hidden serializer).
__device__ __forceinline__ void bar_lds() {
    asm volatile("s_waitcnt lgkmcnt(0)" ::: "memory");
    __builtin_amdgcn_s_barrier();
}

// ---------------- input projection: h = relu(x @ W_in + b_in), fp32; emit hi/lo ----------------
__global__ __launch_bounds__(256) void k_input_proj(
    const float* __restrict__ x, const float* __restrict__ Wi,
    const float* __restrict__ bi, float* __restrict__ h,
    unsigned short* __restrict__ hhi, unsigned short* __restrict__ hlo)
{
    __shared__ float Ws[FIN * HD];
    __shared__ float xs[16][FIN + 1];
    int tid = threadIdx.x;
    for (int i = tid; i < FIN * HD; i += 256) Ws[i] = Wi[i];
    int base = blockIdx.x * 16;
    for (int i = tid; i < 16 * FIN; i += 256) {
        int nd = i / FIN, k = i - nd * FIN;
        xs[nd][k] = x[(size_t)(base + nd) * FIN + k];
    }
    __syncthreads();
    int j = tid & 127, slot = tid >> 7;
    float bj = bi[j];
    for (int r = 0; r < 8; ++r) {
        int nd = slot * 8 + r;
        float acc = bj;
#pragma unroll
        for (int k = 0; k < FIN; ++k) acc += xs[nd][k] * Ws[k * HD + j];
        acc = fmaxf(acc, 0.f);
        int o = (base + nd) * HD + j;
        h[o] = acc;
        unsigned short hv, lv; split_hl(acc, hv, lv);
        hhi[o] = hv; hlo[o] = lv;
    }
}

// ---------------- CSR build ----------------
__global__ __launch_bounds__(256) void k_hist(const int* __restrict__ a_ei, const int* __restrict__ e_ei,
                                              int* __restrict__ cnt) {
    int g = blockIdx.y;
    int gid = blockIdx.x * 256 + threadIdx.x;
    if (gid >= EE) return;
    const int* ei = g ? e_ei : a_ei;
    atomicAdd(&cnt[g * NN + ei[EE + gid]], 1);
}

__global__ __launch_bounds__(256) void k_scanA(const int* __restrict__ cnt, int* __restrict__ bsum) {
    int g = blockIdx.y, b = blockIdx.x, tid = threadIdx.x;
    int base = b * 1024 + tid * 4;
    int s = 0;
#pragma unroll
    for (int j = 0; j < 4; ++j) {
        int i = base + j;
        if (i < NN) s += cnt[g * NN + i];
    }
    __shared__ int lds[256];
    lds[tid] = s; __syncthreads();
    for (int o = 128; o > 0; o >>= 1) {
        if (tid < o) lds[tid] += lds[tid + o];
        __syncthreads();
    }
    if (tid == 0) bsum[g * SCB + b] = lds[0];
}

__global__ __launch_bounds__(64) void k_scanB(const int* __restrict__ bsum, int* __restrict__ bpre) {
    int tid = threadIdx.x;
    if (tid < 2) {
        int run = 0;
        for (int b = 0; b < SCB; ++b) { bpre[tid * SCB + b] = run; run += bsum[tid * SCB + b]; }
    }
}

__global__ __launch_bounds__(256) void k_scanC(const int* __restrict__ cnt, const int* __restrict__ bpre,
                                               int* __restrict__ cur,
                                               float* __restrict__ da, float* __restrict__ de) {
    int g = blockIdx.y, b = blockIdx.x, tid = threadIdx.x;
    float* dg = g ? de : da;
    int base = b * 1024 + tid * 4;
    int c[4]; int ts = 0;
#pragma unroll
    for (int j = 0; j < 4; ++j) {
        int i = base + j;
        c[j] = (i < NN) ? cnt[g * NN + i] : 0;
        ts += c[j];
    }
    __shared__ int lds[256];
    lds[tid] = ts; __syncthreads();
    for (int o = 1; o < 256; o <<= 1) {
        int v = (tid >= o) ? lds[tid - o] : 0;
        __syncthreads();
        lds[tid] += v;
        __syncthreads();
    }
    int run = lds[tid] - ts + bpre[g * SCB + b];
#pragma unroll
    for (int j = 0; j < 4; ++j) {
        int i = base + j;
        if (i < NN) { cur[g * NN + i] = run; dg[i] = (float)c[j]; run += c[j]; }
    }
}

__global__ __launch_bounds__(256) void k_scatter(
    const int* __restrict__ a_ei, const float* __restrict__ a_ea,
    const int* __restrict__ e_ei, const float* __restrict__ e_ea,
    int* __restrict__ cur, int4* __restrict__ es) {
    int g = blockIdx.y;
    int gid = blockIdx.x * 256 + threadIdx.x;
    if (gid >= EE) return;
    const int* ei = g ? e_ei : a_ei;
    const float* ea = g ? e_ea : a_ea;
    int src = ei[gid], tgt = ei[EE + gid];
    int slot = atomicAdd(&cur[g * NN + tgt], 1);
    es[(size_t)g * EE + slot] = make_int4(src, tgt,
        __float_as_int(ea[2 * gid]), __float_as_int(ea[2 * gid + 1]));
}

// ---------------- fused weight prep (hi/lo, n-major transposed) ----------------
__global__ __launch_bounds__(256) void k_prep_all(
    const float* __restrict__ aW1, const float* __restrict__ eW1,
    const float* __restrict__ aW2, const float* __restrict__ eW2,
    const float* __restrict__ cW,
    unsigned short* __restrict__ W1thi, unsigned short* __restrict__ W1tlo,
    unsigned short* __restrict__ W2thi, unsigned short* __restrict__ W2tlo,
    unsigned short* __restrict__ cWthi, unsigned short* __restrict__ cWtlo) {
    int i = blockIdx.x * 256 + threadIdx.x;
    unsigned short hv, lv;
    if (i < 131072) {                       // W1: 4 x [128n][256k]
        int s = i >> 15, r = i & 32767;
        const float* W = ((s < 2) ? aW1 : eW1) + (size_t)(s & 1) * 258 * HD;
        int n = r >> 8, k = r & 255;
        split_hl(W[k * HD + n], hv, lv);
        W1thi[i] = hv; W1tlo[i] = lv;
    } else if (i < 196608) {                // W2: 2 x [128n][256k] ([W2a;W2e])
        int j = i - 131072;
        int l = j >> 15, r = j & 32767;
        int n = r >> 8, k = r & 255;
        float v = (k < HD) ? aW2[(size_t)l * HD * HD + k * HD + n]
                           : eW2[(size_t)l * HD * HD + (k - HD) * HD + n];
        split_hl(v, hv, lv);
        W2thi[j] = hv; W2tlo[j] = lv;
    } else if (i < 229376) {                // cW: 2 x [128n][128k]
        int j = i - 196608;
        int l = j >> 14, r = j & 16383;
        int n = r >> 7, k = r & 127;
        split_hl(cW[(size_t)l * HD * HD + k * HD + n], hv, lv);
        cWthi[j] = hv; cWtlo[j] = lv;
    }
}

// ---------------- target context (persistent, zf-prefetch only) ----------------
// c[t][n] = sum_k<128 h_t[k] W1[k][n] + b1[n]
__global__ __launch_bounds__(256) void k_ctx(
    const unsigned short* __restrict__ hhi, const unsigned short* __restrict__ hlo,
    const unsigned short* __restrict__ Whi, const unsigned short* __restrict__ Wlo,
    const float* __restrict__ b1, float* __restrict__ cc)
{
    __shared__ __align__(16) unsigned short a_hi[16 * 128], a_lo[16 * 128];
    int tid = threadIdx.x;
    int wave = tid >> 6, lane = tid & 63;
    int l16 = lane & 15, quad = lane >> 4;
    int n0 = wave * 32 + l16, n1 = n0 + 16;

    // persistent B fragments (loaded once per block)
    f16x8 bh[2][4], bl[2][4];
#pragma unroll
    for (int b = 0; b < 2; ++b) {
        int n = wave * 32 + b * 16 + l16;
        const unsigned short* ph = Whi + n * K1 + quad * 8;   // target half: k 0..127
        const unsigned short* pl = Wlo + n * K1 + quad * 8;
#pragma unroll
        for (int kt = 0; kt < 4; ++kt) {
            bh[b][kt] = *(const f16x8*)(ph + kt * 32);
            bl[b][kt] = *(const f16x8*)(pl + kt * 32);
        }
    }
    float vb0 = b1[n0], vb1 = b1[n1];

    int nd = tid >> 4, part = tid & 15;
    int pm = part & 7;
    const unsigned short* hsel = (part < 8) ? hhi : hlo;
    unsigned short* msel = ((part < 8) ? a_hi : a_lo) + nd * 128;
    int c0i = (2 * pm) ^ nd, c1i = (2 * pm + 1) ^ nd;

    int stride = gridDim.x;
    int grp = blockIdx.x;

    // prologue prefetch for first group
    uint4 v0, v1;
    {
        const uint4* gpp = (const uint4*)(hsel + (size_t)(grp * 16 + nd) * HD + pm * 16);
        v0 = gpp[0]; v1 = gpp[1];
    }

    for (; grp < NGRP; grp += stride) {
        __syncthreads();                    // prev-iter MFMA readers done with a_hi/a_lo
        *(uint4*)(msel + c0i * 8) = v0;
        *(uint4*)(msel + c1i * 8) = v1;
        __syncthreads();                    // staged

        // issue next-group prefetch (hidden behind MFMA + store)
        {
            int gnx = grp + stride;
            int pfg = (gnx < NGRP) ? gnx : grp;
            const uint4* gpp = (const uint4*)(hsel + (size_t)(pfg * 16 + nd) * HD + pm * 16);
            v0 = gpp[0]; v1 = gpp[1];
        }

        f32x4 h0 = {0,0,0,0}, h1 = {0,0,0,0}, L0 = {0,0,0,0}, L1 = {0,0,0,0};
#pragma unroll
        for (int kt = 0; kt < 4; ++kt) {
            int ch = ((kt * 4 + quad) ^ l16) * 8;
            f16x8 ah = *(const f16x8*)(a_hi + l16 * 128 + ch);
            f16x8 al = *(const f16x8*)(a_lo + l16 * 128 + ch);
            h0 = MFMA16(ah, bh[0][kt], h0);
            h1 = MFMA16(ah, bh[1][kt], h1);
            L0 = MFMA16(ah, bl[0][kt], L0);
            L0 = MFMA16(al, bh[0][kt], L0);
            L1 = MFMA16(ah, bl[1][kt], L1);
            L1 = MFMA16(al, bh[1][kt], L1);
        }
        int base = grp * 16;
#pragma unroll
        for (int r = 0; r < 4; ++r) {
            int rr = quad * 4 + r;
            float* cp = cc + (size_t)(base + rr) * HD;
            cp[n0] = h0[r] + L0[r] * INV_LOSCALE + vb0;
            cp[n1] = h1[r] + L1[r] * INV_LOSCALE + vb1;
        }
    }
}

// ---------------- edge conv (sorted, src-only K=128, M=32 tiles, counted-vmcnt pipeline) ----------------
// R8-proven: bar_lds barriers + ctx hoist. R10 change: STATIC-COUNT segsum — every row issues
// exactly one atomicAdd (boundary rows add `run`, others add 0.0f = IEEE no-op; interior
// plain-stores converted to atomicAdd, safe since zagg is pre-zeroed and atomically
// accumulated). vmcnt is FIFO: with a DYNAMIC store count (2..33) the compiler's wait for the
// gather G at next staging had to assume the minimum (~vmcnt(2)), draining ~28 in-flight
// atomics (~300-500cy L2 completion) every iteration. Static count (33 younger ops on every
// path) lets it emit vmcnt(~33) — waiting only for G, which landed a full iteration ago.
__global__ __launch_bounds__(256, 3) void k_edge(
    const unsigned short* __restrict__ hhi, const unsigned short* __restrict__ hlo,
    const int4* __restrict__ es,          // sorted by target: (src,tgt,ea0,ea1)
    const unsigned short* __restrict__ Whi, const unsigned short* __restrict__ Wlo, // [128][256]
    const float* __restrict__ W1full,     // rows 256/257 for ea
    const float* __restrict__ cctx,       // [node][128]: tgt half + b1
    float* __restrict__ zagg)
{
    __shared__ __align__(16) unsigned short m_hi[32 * 128];
    __shared__ __align__(16) unsigned short m_lo[32 * 128];
    __shared__ float z_s[32][132];
    __shared__ int   ts_s[32];
    __shared__ float ea_s[2][32];

    int tid = threadIdx.x;
    int wave = tid >> 6, lane = tid & 63;
    int l16 = lane & 15, quad = lane >> 4;
    int n0 = wave * 32 + l16, n1 = n0 + 16;

    // persistent B fragments: source half of W1 (k = 128..255)
    f16x8 bhi[2][4], blo[2][4];
#pragma unroll
    for (int b = 0; b < 2; ++b) {
        int n = wave * 32 + b * 16 + l16;
        const unsigned short* ph = Whi + n * K1 + 128 + quad * 8;
        const unsigned short* pl = Wlo + n * K1 + 128 + quad * 8;
#pragma unroll
        for (int kt = 0; kt < 4; ++kt) {
            bhi[b][kt] = *(const f16x8*)(ph + kt * 32);
            blo[b][kt] = *(const f16x8*)(pl + kt * 32);
        }
    }
    float w256_0 = W1full[256 * HD + n0], w257_0 = W1full[257 * HD + n0];
    float w256_1 = W1full[256 * HD + n1], w257_1 = W1full[257 * HD + n1];

    int row = tid >> 3, part = tid & 7;   // 32 rows x 8 parts (64B each)
    int pm = part & 3;
    const unsigned short* hsel = (part < 4) ? hhi : hlo;
    unsigned short* msel = ((part < 4) ? m_hi : m_lo) + row * 128;
    int sw = row & 15;

    int stride = gridDim.x;
    int tile = blockIdx.x;

    // prologue: q_cur(tile), gather G(tile), q_nxt(tile+stride)
    int4 q_cur = es[tile * 32 + row];
    uint4 G0, G1, G2, G3;
    {
        const uint4* gp = (const uint4*)(hsel + (size_t)q_cur.x * HD + pm * 32);
        G0 = gp[0]; G1 = gp[1]; G2 = gp[2]; G3 = gp[3];
    }
    int tn = tile + stride;
    int4 q_nxt = es[(tn < NT32 ? tn : tile) * 32 + row];

    for (; tile < NT32; tile += stride) {
        bar_lds();                          // A: prev-iter segsum LDS reads done
        if (part == 0) {
            ts_s[row] = q_cur.y;
            ea_s[0][row] = __int_as_float(q_cur.z);
            ea_s[1][row] = __int_as_float(q_cur.w);
        }
        {
            int c0 = (pm * 4 + 0) ^ sw, c1 = (pm * 4 + 1) ^ sw;
            int c2 = (pm * 4 + 2) ^ sw, c3 = (pm * 4 + 3) ^ sw;
            *(uint4*)(msel + c0 * 8) = G0;
            *(uint4*)(msel + c1 * 8) = G1;
            *(uint4*)(msel + c2 * 8) = G2;
            *(uint4*)(msel + c3 * 8) = G3;
        }
        bar_lds();                          // B: staging visible to all waves

        // hoisted ctx loads — oldest VMEM batch of this iteration (ts_s valid post-B)
        float ctx00[4], ctx01[4], ctx10[4], ctx11[4];
#pragma unroll
        for (int r = 0; r < 4; ++r) {
            int r0 = quad * 4 + r, r1 = r0 + 16;
            const float* cp0 = cctx + (size_t)ts_s[r0] * HD;
            const float* cp1 = cctx + (size_t)ts_s[r1] * HD;
            ctx00[r] = cp0[n0]; ctx01[r] = cp0[n1];
            ctx10[r] = cp1[n0]; ctx11[r] = cp1[n1];
        }
        __builtin_amdgcn_sched_barrier(0);  // pin: ctx issued before gather/es below

        // gather for next tile + es two ahead — ride across C/A, waited at next staging
        {
            const uint4* gp = (const uint4*)(hsel + (size_t)q_nxt.x * HD + pm * 32);
            G0 = gp[0]; G1 = gp[1]; G2 = gp[2]; G3 = gp[3];
        }
        int t2 = tile + 2 * stride;
        int4 q_tmp = es[(t2 < NT32 ? t2 : tile) * 32 + row];

        f32x4 aH0 = {0,0,0,0}, aH1 = {0,0,0,0}, aH2 = {0,0,0,0}, aH3 = {0,0,0,0};
        f32x4 aL0 = {0,0,0,0}, aL1 = {0,0,0,0}, aL2 = {0,0,0,0}, aL3 = {0,0,0,0};
#pragma unroll
        for (int kt = 0; kt < 4; ++kt) {
            int ch = ((kt * 4 + quad) ^ l16) * 8;
            f16x8 a0h = *(const f16x8*)(m_hi + l16 * 128 + ch);
            f16x8 a0l = *(const f16x8*)(m_lo + l16 * 128 + ch);
            f16x8 a1h = *(const f16x8*)(m_hi + (l16 + 16) * 128 + ch);
            f16x8 a1l = *(const f16x8*)(m_lo + (l16 + 16) * 128 + ch);
            aH0 = MFMA16(a0h, bhi[0][kt], aH0);
            aH1 = MFMA16(a0h, bhi[1][kt], aH1);
            aH2 = MFMA16(a1h, bhi[0][kt], aH2);
            aH3 = MFMA16(a1h, bhi[1][kt], aH3);
            aL0 = MFMA16(a0h, blo[0][kt], aL0);
            aL0 = MFMA16(a0l, bhi[0][kt], aL0);
            aL1 = MFMA16(a0h, blo[1][kt], aL1);
            aL1 = MFMA16(a0l, bhi[1][kt], aL1);
            aL2 = MFMA16(a1h, blo[0][kt], aL2);
            aL2 = MFMA16(a1l, bhi[0][kt], aL2);
            aL3 = MFMA16(a1h, blo[1][kt], aL3);
            aL3 = MFMA16(a1l, bhi[1][kt], aL3);
        }

        // epilogue: + c[tgt] (hoisted regs) + ea rank-2, relu -> z_s
#pragma unroll
        for (int r = 0; r < 4; ++r) {
            int r0 = quad * 4 + r, r1 = r0 + 16;
            float e00 = ea_s[0][r0], e01 = ea_s[1][r0];
            float e10 = ea_s[0][r1], e11 = ea_s[1][r1];
            z_s[r0][n0] = fmaxf(aH0[r] + aL0[r] * INV_LOSCALE + ctx00[r] + e00 * w256_0 + e01 * w257_0, 0.f);
            z_s[r0][n1] = fmaxf(aH1[r] + aL1[r] * INV_LOSCALE + ctx01[r] + e00 * w256_1 + e01 * w257_1, 0.f);
            z_s[r1][n0] = fmaxf(aH2[r] + aL2[r] * INV_LOSCALE + ctx10[r] + e10 * w256_0 + e11 * w257_0, 0.f);
            z_s[r1][n1] = fmaxf(aH3[r] + aL3[r] * INV_LOSCALE + ctx11[r] + e10 * w256_1 + e11 * w257_1, 0.f);
        }
        bar_lds();                          // C: z_s visible

        // segmented sum over 32 sorted rows — STATIC VMEM COUNT: exactly 32 atomicAdd/thread
        if (tid < 128) {
            int c = tid;
            float run = z_s[0][c];
            int tp = ts_s[0];
#pragma unroll
            for (int r = 1; r < 32; ++r) {
                int t = ts_s[r];
                float v = z_s[r][c];
                bool bnd = (t != tp);
                atomicAdd(zagg + (size_t)tp * HD + c, bnd ? run : 0.0f);  // 0-add = IEEE no-op
                run = bnd ? v : (run + v);
                tp = t;
            }
            atomicAdd(zagg + (size_t)tp * HD + c, run);
        }

        q_cur = q_nxt; q_nxt = q_tmp;
    }
}

// ---------------- node update (persistent; R9-proven bar_lds + loop-top h/da/de hoist) ----------------
__global__ __launch_bounds__(256) void k_node(
    float* __restrict__ h,
    unsigned short* __restrict__ hhi, unsigned short* __restrict__ hlo,
    const float* __restrict__ za, const float* __restrict__ ze,
    const float* __restrict__ da, const float* __restrict__ de,
    const unsigned short* __restrict__ W2hi, const unsigned short* __restrict__ W2lo,
    const float* __restrict__ b2a, const float* __restrict__ b2e,
    const float* __restrict__ g, const float* __restrict__ bln,
    const unsigned short* __restrict__ cWhi, const unsigned short* __restrict__ cWlo,
    const float* __restrict__ cb)
{
    __shared__ __align__(16) unsigned short a_hi[16][264], a_lo[16][264];
    __shared__ float t1_s[16][132];
    __shared__ __align__(16) unsigned short u_hi[16][136], u_lo[16][136];
    __shared__ float g_s[HD], b_s[HD];
    int tid = threadIdx.x;
    int wave = tid >> 6, lane = tid & 63;
    int l16 = lane & 15, quad = lane >> 4;
    int nb0 = wave * 2;
    int n0 = nb0 * 16 + l16, n1 = n0 + 16;

    if (tid < HD) { g_s[tid] = g[tid]; b_s[tid] = bln[tid]; }

    // persistent weight fragments (W2 + cW in registers, once per block)
    f16x8 b2h[2][8], b2l[2][8], bch[2][4], bcl[2][4];
#pragma unroll
    for (int b = 0; b < 2; ++b) {
        int n = (nb0 + b) * 16 + l16;
        const unsigned short* p2h = W2hi + n * 256 + quad * 8;
        const unsigned short* p2l = W2lo + n * 256 + quad * 8;
#pragma unroll
        for (int kt = 0; kt < 8; ++kt) {
            b2h[b][kt] = *(const f16x8*)(p2h + kt * 32);
            b2l[b][kt] = *(const f16x8*)(p2l + kt * 32);
        }
        const unsigned short* pch = cWhi + n * 128 + quad * 8;
        const unsigned short* pcl = cWlo + n * 128 + quad * 8;
#pragma unroll
        for (int kt = 0; kt < 4; ++kt) {
            bch[b][kt] = *(const f16x8*)(pch + kt * 32);
            bcl[b][kt] = *(const f16x8*)(pcl + kt * 32);
        }
    }
    float vb2a0 = b2a[n0], vb2a1 = b2a[n1];
    float vb2e0 = b2e[n0], vb2e1 = b2e[n1];
    float vcb0 = cb[n0], vcb1 = cb[n1];

    int nd = tid >> 4, part = tid & 15;
    const float* zsel = (part < 8) ? za : ze;
    int pq = part & 7;

    int stride = gridDim.x;
    int grp = blockIdx.x;

    // prologue prefetch of za/ze for first group
    float4 zf0, zf1, zf2, zf3;
    {
        const float4* sp = (const float4*)(zsel + (size_t)(grp * 16 + nd) * HD + pq * 16);
        zf0 = sp[0]; zf1 = sp[1]; zf2 = sp[2]; zf3 = sp[3];
    }

    for (; grp < NGRP; grp += stride) {
        int base = grp * 16;

        // hoisted current-group h/da/de — oldest VMEM batch of this iteration
        float hp[8], dav[4], dev[4];
#pragma unroll
        for (int r = 0; r < 4; ++r) {
            const float* hb = h + (size_t)(base + quad * 4 + r) * HD;
            hp[2 * r]     = hb[n0];
            hp[2 * r + 1] = hb[n1];
            dav[r] = da[base + quad * 4 + r];
            dev[r] = de[base + quad * 4 + r];
        }
        __builtin_amdgcn_sched_barrier(0);  // pin: h/da/de issued before anything below

        bar_lds();                          // S0: prev-iter P1 done reading a_*

        // ---- P0: split prefetched za/ze -> LDS ----
        {
            union { unsigned short s[16]; uint4 q[2]; } Hv, Lv;
            float4 fa[4] = {zf0, zf1, zf2, zf3};
#pragma unroll
            for (int i = 0; i < 4; ++i) {
                split_hl(fa[i].x, Hv.s[4*i+0], Lv.s[4*i+0]);
                split_hl(fa[i].y, Hv.s[4*i+1], Lv.s[4*i+1]);
                split_hl(fa[i].z, Hv.s[4*i+2], Lv.s[4*i+2]);
                split_hl(fa[i].w, Hv.s[4*i+3], Lv.s[4*i+3]);
            }
            int ko = part * 16;
            *(uint4*)&a_hi[nd][ko] = Hv.q[0]; *(uint4*)&a_hi[nd][ko + 8] = Hv.q[1];
            *(uint4*)&a_lo[nd][ko] = Lv.q[0]; *(uint4*)&a_lo[nd][ko + 8] = Lv.q[1];
        }
        bar_lds();                          // S1: staged

        // issue next-group za/ze prefetch (rides across S2/S3/S0)
        {
            int gnx = grp + stride;
            int pfg = (gnx < NGRP) ? gnx : grp;   // clamped; tail values unused
            const float4* sp = (const float4*)(zsel + (size_t)(pfg * 16 + nd) * HD + pq * 16);
            zf0 = sp[0]; zf1 = sp[1]; zf2 = sp[2]; zf3 = sp[3];
        }

        // ---- P1: [za|ze] @ [W2a;W2e] (K=256); h/da/de from hoisted regs ----
        f32x4 acc0 = {0,0,0,0}, acc1 = {0,0,0,0}, accL0 = {0,0,0,0}, accL1 = {0,0,0,0};
#pragma unroll
        for (int kt = 0; kt < 8; ++kt) {
            f16x8 ah = *(const f16x8*)&a_hi[l16][kt * 32 + quad * 8];
            f16x8 al = *(const f16x8*)&a_lo[l16][kt * 32 + quad * 8];
            acc0  = MFMA16(ah, b2h[0][kt], acc0);
            acc1  = MFMA16(ah, b2h[1][kt], acc1);
            accL0 = MFMA16(ah, b2l[0][kt], accL0);
            accL1 = MFMA16(ah, b2l[1][kt], accL1);
            accL0 = MFMA16(al, b2h[0][kt], accL0);
            accL1 = MFMA16(al, b2h[1][kt], accL1);
        }
#pragma unroll
        for (int r = 0; r < 4; ++r) {
            int ndl = quad * 4 + r;
            t1_s[ndl][n0] = acc0[r] + accL0[r] * INV_LOSCALE + hp[2 * r]     + dav[r] * vb2a0 + dev[r] * vb2e0;
            t1_s[ndl][n1] = acc1[r] + accL1[r] * INV_LOSCALE + hp[2 * r + 1] + dav[r] * vb2a1 + dev[r] * vb2e1;
        }
        bar_lds();                          // S2: t1 ready

        // ---- P2: LayerNorm ----
        float v[8]; float s = 0.f, ss = 0.f;
#pragma unroll
        for (int i = 0; i < 8; ++i) { v[i] = t1_s[nd][part * 8 + i]; s += v[i]; ss += v[i] * v[i]; }
#pragma unroll
        for (int m = 1; m < 16; m <<= 1) { s += __shfl_xor(s, m); ss += __shfl_xor(ss, m); }
        float mu = s * (1.f / HD);
        float var = ss * (1.f / HD) - mu * mu;
        float inv = rsqrtf(var + 1e-5f);
        {
            union { unsigned short s[8]; uint4 q; } Hu, Lu;
#pragma unroll
            for (int i = 0; i < 8; ++i) {
                int c = part * 8 + i;
                float u = (v[i] - mu) * inv * g_s[c] + b_s[c];
                t1_s[nd][c] = u;
                split_hl(u, Hu.s[i], Lu.s[i]);
            }
            *(uint4*)&u_hi[nd][part * 8] = Hu.q;
            *(uint4*)&u_lo[nd][part * 8] = Lu.q;
        }
        bar_lds();                          // S3: u ready

        // ---- P3: comb MFMA (persistent bch/bcl) ----
        f32x4 c0 = {0,0,0,0}, c1 = {0,0,0,0}, cL0 = {0,0,0,0}, cL1 = {0,0,0,0};
#pragma unroll
        for (int kt = 0; kt < 4; ++kt) {
            f16x8 ah = *(const f16x8*)&u_hi[l16][kt * 32 + quad * 8];
            f16x8 al = *(const f16x8*)&u_lo[l16][kt * 32 + quad * 8];
            c0  = MFMA16(ah, bch[0][kt], c0);
            c1  = MFMA16(ah, bch[1][kt], c1);
            cL0 = MFMA16(ah, bcl[0][kt], cL0);
            cL1 = MFMA16(ah, bcl[1][kt], cL1);
            cL0 = MFMA16(al, bch[0][kt], cL0);
            cL1 = MFMA16(al, bch[1][kt], cL1);
        }
#pragma unroll
        for (int r = 0; r < 4; ++r) {
            int ndl = quad * 4 + r;
            int go = (base + ndl) * HD;
            float u0 = t1_s[ndl][n0], u1 = t1_s[ndl][n1];
            float r0 = fmaxf(c0[r] + cL0[r] * INV_LOSCALE + vcb0, 0.f);
            float r1 = fmaxf(c1[r] + cL1[r] * INV_LOSCALE + vcb1, 0.f);
            float o0 = u0 + r0, o1 = u1 + r1;
            h[go + n0] = o0; h[go + n1] = o1;
            unsigned short hv, lv;
            split_hl(o0, hv, lv); hhi[go + n0] = hv; hlo[go + n0] = lv;
            split_hl(o1, hv, lv); hhi[go + n1] = hv; hlo[go + n1] = lv;
        }
    }
}

extern "C" void kernel_launch(void* const* d_in, const int* in_sizes, int n_in,
                              void* d_out, int out_size, void* d_ws, size_t ws_size,
                              hipStream_t stream) {
    const float* x    = (const float*)d_in[0];
    const int*   a_ei = (const int*)d_in[1];
    const float* a_ea = (const float*)d_in[2];
    const int*   e_ei = (const int*)d_in[3];
    const float* e_ea = (const float*)d_in[4];
    const float* W_in = (const float*)d_in[5];
    const float* b_in = (const float*)d_in[6];
    const float* aW1  = (const float*)d_in[7];
    const float* ab1  = (const float*)d_in[8];
    const float* aW2  = (const float*)d_in[9];
    const float* ab2  = (const float*)d_in[10];
    const float* eW1  = (const float*)d_in[11];
    const float* eb1  = (const float*)d_in[12];
    const float* eW2  = (const float*)d_in[13];
    const float* eb2  = (const float*)d_in[14];
    const float* ln_g = (const float*)d_in[15];
    const float* ln_b = (const float*)d_in[16];
    const float* cW   = (const float*)d_in[17];
    const float* cb   = (const float*)d_in[18];
    float* h = (float*)d_out;

    // ---- workspace layout, total ~226 MB ----
    char* ws = (char*)d_ws;
    int4* es = (int4*)ws;                        ws += (size_t)2 * EE * 16;     // 19.2 MB
    unsigned short* hhi = (unsigned short*)ws;   ws += (size_t)NN * HD * 2;     // 25.6 MB
    unsigned short* hlo = (unsigned short*)ws;   ws += (size_t)NN * HD * 2;     // 25.6 MB
    float* zagg_a = (float*)ws;                  ws += (size_t)NN * HD * 4;     // 51.2 MB
    float* zagg_e = (float*)ws;                  ws += (size_t)NN * HD * 4;     // 51.2 MB
    float* ctx = (float*)ws;                     ws += (size_t)NN * HD * 4;     // 51.2 MB (shared per graph)
    unsigned short* W1thi = (unsigned short*)ws; ws += (size_t)4 * HD * K1 * 2;
    unsigned short* W1tlo = (unsigned short*)ws; ws += (size_t)4 * HD * K1 * 2;
    unsigned short* W2thi = (unsigned short*)ws; ws += (size_t)2 * HD * 256 * 2;
    unsigned short* W2tlo = (unsigned short*)ws; ws += (size_t)2 * HD * 256 * 2;
    unsigned short* cWthi = (unsigned short*)ws; ws += (size_t)2 * HD * HD * 2;
    unsigned short* cWtlo = (unsigned short*)ws; ws += (size_t)2 * HD * HD * 2;
    float* da = (float*)ws;                      ws += (size_t)NN * 4;
    float* de = (float*)ws;                      ws += (size_t)NN * 4;
    // CSR-build scratch aliased into ctx (dead before first k_ctx writes ctx)
    int* cnt = (int*)ctx;
    int* cur = cnt + 2 * NN;
    int* bsum = cur + 2 * NN;
    int* bpre = bsum + 2 * SCB;

    k_input_proj<<<NN / 16, 256, 0, stream>>>(x, W_in, b_in, h, hhi, hlo);

    // CSR build (once per launch; reused by both layers)
    hipMemsetAsync(cnt, 0, (size_t)2 * NN * 4, stream);
    dim3 ge((EE + 255) / 256, 2);
    k_hist<<<ge, 256, 0, stream>>>(a_ei, e_ei, cnt);
    dim3 gs(SCB, 2);
    k_scanA<<<gs, 256, 0, stream>>>(cnt, bsum);
    k_scanB<<<1, 64, 0, stream>>>(bsum, bpre);
    k_scanC<<<gs, 256, 0, stream>>>(cnt, bpre, cur, da, de);
    k_scatter<<<ge, 256, 0, stream>>>(a_ei, a_ea, e_ei, e_ea, cur, es);

    k_prep_all<<<896, 256, 0, stream>>>(aW1, eW1, aW2, eW2, cW,
                                        W1thi, W1tlo, W2thi, W2tlo, cWthi, cWtlo);

    const int W1SZ = (2 * HD + 2) * HD;
    for (int l = 0; l < 2; ++l) {
        hipMemsetAsync(zagg_a, 0, (size_t)2 * NN * HD * 4, stream);  // zagg_a + zagg_e adjacent
        k_ctx<<<1024, 256, 0, stream>>>(hhi, hlo,
            W1thi + (0 + l) * HD * K1, W1tlo + (0 + l) * HD * K1, ab1 + l * HD, ctx);
        k_edge<<<2048, 256, 0, stream>>>(hhi, hlo, es,
            W1thi + (0 + l) * HD * K1, W1tlo + (0 + l) * HD * K1,
            aW1 + (size_t)l * W1SZ, ctx, zagg_a);
        k_ctx<<<1024, 256, 0, stream>>>(hhi, hlo,
            W1thi + (2 + l) * HD * K1, W1tlo + (2 + l) * HD * K1, eb1 + l * HD, ctx);
        k_edge<<<2048, 256, 0, stream>>>(hhi, hlo, es + (size_t)EE,
            W1thi + (2 + l) * HD * K1, W1tlo + (2 + l) * HD * K1,
            eW1 + (size_t)l * W1SZ, ctx, zagg_e);
        k_node<<<512, 256, 0, stream>>>(h, hhi, hlo, zagg_a, zagg_e, da, de,
            W2thi + l * HD * 256, W2tlo + l * HD * 256, ab2 + l * HD, eb2 + l * HD,
            ln_g + l * HD, ln_b + l * HD,
            cWthi + l * HD * HD, cWtlo + l * HD * HD, cb + l * HD);
    }
}

// Round 11
// 1334.051 us; speedup vs baseline: 1.3231x; 1.3231x over previous
//
#include <hip/hip_runtime.h>

#define NN 100000
#define EE 600000
#define FIN 39
#define HD 128
#define K1 256          // W1t layout K (k<128 = target half, k>=128 = source half)
#define NT32 (EE / 32)  // 18750 edge tiles of 32
#define NGRP (NN / 16)  // 6250 node groups of 16
#define LOSCALE 4096.0f
#define INV_LOSCALE (1.0f / 4096.0f)
#define SCB 98          // scan blocks per graph: 98*1024 >= NN

typedef _Float16 f16x8 __attribute__((ext_vector_type(8)));
typedef __attribute__((ext_vector_type(4))) float f32x4;

#define MFMA16(a, b, c) __builtin_amdgcn_mfma_f32_16x16x32_f16((a), (b), (c), 0, 0, 0)

__device__ __forceinline__ void split_hl(float x, unsigned short& hi, unsigned short& lo) {
    union { _Float16 h; unsigned short u; } a, b;
    a.h = (_Float16)x;
    float r = (x - (float)a.h) * LOSCALE;   // scaled residual stays fp16-normal
    b.h = (_Float16)r;
    hi = a.u; lo = b.u;
}

// LDS-only barrier: drains LDS ops (cross-wave staging visibility) but leaves VMEM
// loads in flight. __syncthreads() would emit s_waitcnt vmcnt(0) before s_barrier,
// force-draining the gather prefetch every phase (the R2..R6 hidden serializer).
__device__ __forceinline__ void bar_lds() {
    asm volatile("s_waitcnt lgkmcnt(0)" ::: "memory");
    __builtin_amdgcn_s_barrier();
}

// ---------------- input projection: h = relu(x @ W_in + b_in), fp32; emit hi/lo ----------------
__global__ __launch_bounds__(256) void k_input_proj(
    const float* __restrict__ x, const float* __restrict__ Wi,
    const float* __restrict__ bi, float* __restrict__ h,
    unsigned short* __restrict__ hhi, unsigned short* __restrict__ hlo)
{
    __shared__ float Ws[FIN * HD];
    __shared__ float xs[16][FIN + 1];
    int tid = threadIdx.x;
    for (int i = tid; i < FIN * HD; i += 256) Ws[i] = Wi[i];
    int base = blockIdx.x * 16;
    for (int i = tid; i < 16 * FIN; i += 256) {
        int nd = i / FIN, k = i - nd * FIN;
        xs[nd][k] = x[(size_t)(base + nd) * FIN + k];
    }
    __syncthreads();
    int j = tid & 127, slot = tid >> 7;
    float bj = bi[j];
    for (int r = 0; r < 8; ++r) {
        int nd = slot * 8 + r;
        float acc = bj;
#pragma unroll
        for (int k = 0; k < FIN; ++k) acc += xs[nd][k] * Ws[k * HD + j];
        acc = fmaxf(acc, 0.f);
        int o = (base + nd) * HD + j;
        h[o] = acc;
        unsigned short hv, lv; split_hl(acc, hv, lv);
        hhi[o] = hv; hlo[o] = lv;
    }
}

// ---------------- CSR build ----------------
__global__ __launch_bounds__(256) void k_hist(const int* __restrict__ a_ei, const int* __restrict__ e_ei,
                                              int* __restrict__ cnt) {
    int g = blockIdx.y;
    int gid = blockIdx.x * 256 + threadIdx.x;
    if (gid >= EE) return;
    const int* ei = g ? e_ei : a_ei;
    atomicAdd(&cnt[g * NN + ei[EE + gid]], 1);
}

__global__ __launch_bounds__(256) void k_scanA(const int* __restrict__ cnt, int* __restrict__ bsum) {
    int g = blockIdx.y, b = blockIdx.x, tid = threadIdx.x;
    int base = b * 1024 + tid * 4;
    int s = 0;
#pragma unroll
    for (int j = 0; j < 4; ++j) {
        int i = base + j;
        if (i < NN) s += cnt[g * NN + i];
    }
    __shared__ int lds[256];
    lds[tid] = s; __syncthreads();
    for (int o = 128; o > 0; o >>= 1) {
        if (tid < o) lds[tid] += lds[tid + o];
        __syncthreads();
    }
    if (tid == 0) bsum[g * SCB + b] = lds[0];
}

__global__ __launch_bounds__(64) void k_scanB(const int* __restrict__ bsum, int* __restrict__ bpre) {
    int tid = threadIdx.x;
    if (tid < 2) {
        int run = 0;
        for (int b = 0; b < SCB; ++b) { bpre[tid * SCB + b] = run; run += bsum[tid * SCB + b]; }
    }
}

__global__ __launch_bounds__(256) void k_scanC(const int* __restrict__ cnt, const int* __restrict__ bpre,
                                               int* __restrict__ cur,
                                               float* __restrict__ da, float* __restrict__ de) {
    int g = blockIdx.y, b = blockIdx.x, tid = threadIdx.x;
    float* dg = g ? de : da;
    int base = b * 1024 + tid * 4;
    int c[4]; int ts = 0;
#pragma unroll
    for (int j = 0; j < 4; ++j) {
        int i = base + j;
        c[j] = (i < NN) ? cnt[g * NN + i] : 0;
        ts += c[j];
    }
    __shared__ int lds[256];
    lds[tid] = ts; __syncthreads();
    for (int o = 1; o < 256; o <<= 1) {
        int v = (tid >= o) ? lds[tid - o] : 0;
        __syncthreads();
        lds[tid] += v;
        __syncthreads();
    }
    int run = lds[tid] - ts + bpre[g * SCB + b];
#pragma unroll
    for (int j = 0; j < 4; ++j) {
        int i = base + j;
        if (i < NN) { cur[g * NN + i] = run; dg[i] = (float)c[j]; run += c[j]; }
    }
}

__global__ __launch_bounds__(256) void k_scatter(
    const int* __restrict__ a_ei, const float* __restrict__ a_ea,
    const int* __restrict__ e_ei, const float* __restrict__ e_ea,
    int* __restrict__ cur, int4* __restrict__ es) {
    int g = blockIdx.y;
    int gid = blockIdx.x * 256 + threadIdx.x;
    if (gid >= EE) return;
    const int* ei = g ? e_ei : a_ei;
    const float* ea = g ? e_ea : a_ea;
    int src = ei[gid], tgt = ei[EE + gid];
    int slot = atomicAdd(&cur[g * NN + tgt], 1);
    es[(size_t)g * EE + slot] = make_int4(src, tgt,
        __float_as_int(ea[2 * gid]), __float_as_int(ea[2 * gid + 1]));
}

// ---------------- fused weight prep (hi/lo, n-major transposed) ----------------
__global__ __launch_bounds__(256) void k_prep_all(
    const float* __restrict__ aW1, const float* __restrict__ eW1,
    const float* __restrict__ aW2, const float* __restrict__ eW2,
    const float* __restrict__ cW,
    unsigned short* __restrict__ W1thi, unsigned short* __restrict__ W1tlo,
    unsigned short* __restrict__ W2thi, unsigned short* __restrict__ W2tlo,
    unsigned short* __restrict__ cWthi, unsigned short* __restrict__ cWtlo) {
    int i = blockIdx.x * 256 + threadIdx.x;
    unsigned short hv, lv;
    if (i < 131072) {                       // W1: 4 x [128n][256k]
        int s = i >> 15, r = i & 32767;
        const float* W = ((s < 2) ? aW1 : eW1) + (size_t)(s & 1) * 258 * HD;
        int n = r >> 8, k = r & 255;
        split_hl(W[k * HD + n], hv, lv);
        W1thi[i] = hv; W1tlo[i] = lv;
    } else if (i < 196608) {                // W2: 2 x [128n][256k] ([W2a;W2e])
        int j = i - 131072;
        int l = j >> 15, r = j & 32767;
        int n = r >> 8, k = r & 255;
        float v = (k < HD) ? aW2[(size_t)l * HD * HD + k * HD + n]
                           : eW2[(size_t)l * HD * HD + (k - HD) * HD + n];
        split_hl(v, hv, lv);
        W2thi[j] = hv; W2tlo[j] = lv;
    } else if (i < 229376) {                // cW: 2 x [128n][128k]
        int j = i - 196608;
        int l = j >> 14, r = j & 16383;
        int n = r >> 7, k = r & 127;
        split_hl(cW[(size_t)l * HD * HD + k * HD + n], hv, lv);
        cWthi[j] = hv; cWtlo[j] = lv;
    }
}

// ---------------- target context (persistent, zf-prefetch only) ----------------
// c[t][n] = sum_k<128 h_t[k] W1[k][n] + b1[n]
__global__ __launch_bounds__(256) void k_ctx(
    const unsigned short* __restrict__ hhi, const unsigned short* __restrict__ hlo,
    const unsigned short* __restrict__ Whi, const unsigned short* __restrict__ Wlo,
    const float* __restrict__ b1, float* __restrict__ cc)
{
    __shared__ __align__(16) unsigned short a_hi[16 * 128], a_lo[16 * 128];
    int tid = threadIdx.x;
    int wave = tid >> 6, lane = tid & 63;
    int l16 = lane & 15, quad = lane >> 4;
    int n0 = wave * 32 + l16, n1 = n0 + 16;

    // persistent B fragments (loaded once per block)
    f16x8 bh[2][4], bl[2][4];
#pragma unroll
    for (int b = 0; b < 2; ++b) {
        int n = wave * 32 + b * 16 + l16;
        const unsigned short* ph = Whi + n * K1 + quad * 8;   // target half: k 0..127
        const unsigned short* pl = Wlo + n * K1 + quad * 8;
#pragma unroll
        for (int kt = 0; kt < 4; ++kt) {
            bh[b][kt] = *(const f16x8*)(ph + kt * 32);
            bl[b][kt] = *(const f16x8*)(pl + kt * 32);
        }
    }
    float vb0 = b1[n0], vb1 = b1[n1];

    int nd = tid >> 4, part = tid & 15;
    int pm = part & 7;
    const unsigned short* hsel = (part < 8) ? hhi : hlo;
    unsigned short* msel = ((part < 8) ? a_hi : a_lo) + nd * 128;
    int c0i = (2 * pm) ^ nd, c1i = (2 * pm + 1) ^ nd;

    int stride = gridDim.x;
    int grp = blockIdx.x;

    // prologue prefetch for first group
    uint4 v0, v1;
    {
        const uint4* gpp = (const uint4*)(hsel + (size_t)(grp * 16 + nd) * HD + pm * 16);
        v0 = gpp[0]; v1 = gpp[1];
    }

    for (; grp < NGRP; grp += stride) {
        __syncthreads();                    // prev-iter MFMA readers done with a_hi/a_lo
        *(uint4*)(msel + c0i * 8) = v0;
        *(uint4*)(msel + c1i * 8) = v1;
        __syncthreads();                    // staged

        // issue next-group prefetch (hidden behind MFMA + store)
        {
            int gnx = grp + stride;
            int pfg = (gnx < NGRP) ? gnx : grp;
            const uint4* gpp = (const uint4*)(hsel + (size_t)(pfg * 16 + nd) * HD + pm * 16);
            v0 = gpp[0]; v1 = gpp[1];
        }

        f32x4 h0 = {0,0,0,0}, h1 = {0,0,0,0}, L0 = {0,0,0,0}, L1 = {0,0,0,0};
#pragma unroll
        for (int kt = 0; kt < 4; ++kt) {
            int ch = ((kt * 4 + quad) ^ l16) * 8;
            f16x8 ah = *(const f16x8*)(a_hi + l16 * 128 + ch);
            f16x8 al = *(const f16x8*)(a_lo + l16 * 128 + ch);
            h0 = MFMA16(ah, bh[0][kt], h0);
            h1 = MFMA16(ah, bh[1][kt], h1);
            L0 = MFMA16(ah, bl[0][kt], L0);
            L0 = MFMA16(al, bh[0][kt], L0);
            L1 = MFMA16(ah, bl[1][kt], L1);
            L1 = MFMA16(al, bh[1][kt], L1);
        }
        int base = grp * 16;
#pragma unroll
        for (int r = 0; r < 4; ++r) {
            int rr = quad * 4 + r;
            float* cp = cc + (size_t)(base + rr) * HD;
            cp[n0] = h0[r] + L0[r] * INV_LOSCALE + vb0;
            cp[n1] = h1[r] + L1[r] * INV_LOSCALE + vb1;
        }
    }
}

// ---------------- edge conv (sorted, src-only K=128, M=32 tiles, deferred-segsum pipeline) ----------------
// R11: R9's segsum (dynamic atomics — R10's zero-atomics quintupled WRITE traffic, reverted)
// DEFERRED one iteration with double-buffered z_s/ts_s. New order per iter:
//   A -> stage(i) [waits G(i): younger = es only -> vmcnt(1)] -> B -> segsum(i-1) [dynamic
//   atomics, now OLDER than everything waited on] -> ctx(i) [younger = G+es = static 5] ->
//   sched_barrier -> issue G(i+1)+es -> MFMA(i) -> epilogue(i)->z[p].
// The G-wait no longer drains the atomic queue (R9's residual stall), and the C barrier is
// gone (segsum reads z across next iter's A+B). Rotation: z[p] write (epi i) vs z[p] read
// (segsum i-2 at iter i-1) separated by A(i),B(i); m write (stage i) vs MFMA(i-1) read
// separated by A(i); ts/ea analogous. LDS ~50.7KB -> still 3 blocks/CU. FP math identical.
__global__ __launch_bounds__(256, 3) void k_edge(
    const unsigned short* __restrict__ hhi, const unsigned short* __restrict__ hlo,
    const int4* __restrict__ es,          // sorted by target: (src,tgt,ea0,ea1)
    const unsigned short* __restrict__ Whi, const unsigned short* __restrict__ Wlo, // [128][256]
    const float* __restrict__ W1full,     // rows 256/257 for ea
    const float* __restrict__ cctx,       // [node][128]: tgt half + b1
    float* __restrict__ zagg)
{
    __shared__ __align__(16) unsigned short m_hi[32 * 128];
    __shared__ __align__(16) unsigned short m_lo[32 * 128];
    __shared__ float z_s[2][32][132];
    __shared__ int   ts_s[2][32];
    __shared__ float ea_s[2][32];

    int tid = threadIdx.x;
    int wave = tid >> 6, lane = tid & 63;
    int l16 = lane & 15, quad = lane >> 4;
    int n0 = wave * 32 + l16, n1 = n0 + 16;

    // persistent B fragments: source half of W1 (k = 128..255)
    f16x8 bhi[2][4], blo[2][4];
#pragma unroll
    for (int b = 0; b < 2; ++b) {
        int n = wave * 32 + b * 16 + l16;
        const unsigned short* ph = Whi + n * K1 + 128 + quad * 8;
        const unsigned short* pl = Wlo + n * K1 + 128 + quad * 8;
#pragma unroll
        for (int kt = 0; kt < 4; ++kt) {
            bhi[b][kt] = *(const f16x8*)(ph + kt * 32);
            blo[b][kt] = *(const f16x8*)(pl + kt * 32);
        }
    }
    float w256_0 = W1full[256 * HD + n0], w257_0 = W1full[257 * HD + n0];
    float w256_1 = W1full[256 * HD + n1], w257_1 = W1full[257 * HD + n1];

    int row = tid >> 3, part = tid & 7;   // 32 rows x 8 parts (64B each)
    int pm = part & 3;
    const unsigned short* hsel = (part < 4) ? hhi : hlo;
    unsigned short* msel = ((part < 4) ? m_hi : m_lo) + row * 128;
    int sw = row & 15;

    int stride = gridDim.x;
    int tile = blockIdx.x;
    int p = 0;

    // prologue: q_cur(tile), gather G(tile), q_nxt(tile+stride)
    int4 q_cur = es[tile * 32 + row];
    uint4 G0, G1, G2, G3;
    {
        const uint4* gp = (const uint4*)(hsel + (size_t)q_cur.x * HD + pm * 32);
        G0 = gp[0]; G1 = gp[1]; G2 = gp[2]; G3 = gp[3];
    }
    int tn = tile + stride;
    int4 q_nxt = es[(tn < NT32 ? tn : tile) * 32 + row];

    for (; tile < NT32; tile += stride) {
        bar_lds();                          // A: MFMA(i-1) m-reads + z[p] last readers done
        if (part == 0) {
            ts_s[p][row] = q_cur.y;
            ea_s[0][row] = __int_as_float(q_cur.z);
            ea_s[1][row] = __int_as_float(q_cur.w);
        }
        {
            int c0 = (pm * 4 + 0) ^ sw, c1 = (pm * 4 + 1) ^ sw;
            int c2 = (pm * 4 + 2) ^ sw, c3 = (pm * 4 + 3) ^ sw;
            *(uint4*)(msel + c0 * 8) = G0;
            *(uint4*)(msel + c1 * 8) = G1;
            *(uint4*)(msel + c2 * 8) = G2;
            *(uint4*)(msel + c3 * 8) = G3;
        }
        bar_lds();                          // B: staging visible

        // deferred segsum for PREVIOUS tile (dynamic atomics; oldest VMEM batch this iter)
        if (tile != (int)blockIdx.x) {      // uniform: skip on first iteration
            if (tid < 128) {
                int c = tid;
                int pp = p ^ 1;
                float run = z_s[pp][0][c];
                int tp = ts_s[pp][0];
                bool open0 = true;
#pragma unroll
                for (int r = 1; r < 32; ++r) {
                    int t = ts_s[pp][r];
                    float v = z_s[pp][r][c];
                    if (t == tp) { run += v; }
                    else {
                        float* pz = zagg + (size_t)tp * HD + c;
                        if (open0) atomicAdd(pz, run);
                        else       *pz = run;
                        run = v; tp = t; open0 = false;
                    }
                }
                atomicAdd(zagg + (size_t)tp * HD + c, run);
            }
        }

        // ctx loads for THIS tile (after atomics -> epilogue wait is static vmcnt(5))
        float ctx00[4], ctx01[4], ctx10[4], ctx11[4];
#pragma unroll
        for (int r = 0; r < 4; ++r) {
            int r0 = quad * 4 + r, r1 = r0 + 16;
            const float* cp0 = cctx + (size_t)ts_s[p][r0] * HD;
            const float* cp1 = cctx + (size_t)ts_s[p][r1] * HD;
            ctx00[r] = cp0[n0]; ctx01[r] = cp0[n1];
            ctx10[r] = cp1[n0]; ctx11[r] = cp1[n1];
        }
        __builtin_amdgcn_sched_barrier(0);  // pin: atomics/ctx issued before gather below

        // gather for next tile + es two ahead — waited only at next staging (vmcnt ~1)
        {
            const uint4* gp = (const uint4*)(hsel + (size_t)q_nxt.x * HD + pm * 32);
            G0 = gp[0]; G1 = gp[1]; G2 = gp[2]; G3 = gp[3];
        }
        int t2 = tile + 2 * stride;
        int4 q_tmp = es[(t2 < NT32 ? t2 : tile) * 32 + row];

        f32x4 aH0 = {0,0,0,0}, aH1 = {0,0,0,0}, aH2 = {0,0,0,0}, aH3 = {0,0,0,0};
        f32x4 aL0 = {0,0,0,0}, aL1 = {0,0,0,0}, aL2 = {0,0,0,0}, aL3 = {0,0,0,0};
#pragma unroll
        for (int kt = 0; kt < 4; ++kt) {
            int ch = ((kt * 4 + quad) ^ l16) * 8;
            f16x8 a0h = *(const f16x8*)(m_hi + l16 * 128 + ch);
            f16x8 a0l = *(const f16x8*)(m_lo + l16 * 128 + ch);
            f16x8 a1h = *(const f16x8*)(m_hi + (l16 + 16) * 128 + ch);
            f16x8 a1l = *(const f16x8*)(m_lo + (l16 + 16) * 128 + ch);
            aH0 = MFMA16(a0h, bhi[0][kt], aH0);
            aH1 = MFMA16(a0h, bhi[1][kt], aH1);
            aH2 = MFMA16(a1h, bhi[0][kt], aH2);
            aH3 = MFMA16(a1h, bhi[1][kt], aH3);
            aL0 = MFMA16(a0h, blo[0][kt], aL0);
            aL0 = MFMA16(a0l, bhi[0][kt], aL0);
            aL1 = MFMA16(a0h, blo[1][kt], aL1);
            aL1 = MFMA16(a0l, bhi[1][kt], aL1);
            aL2 = MFMA16(a1h, blo[0][kt], aL2);
            aL2 = MFMA16(a1l, bhi[0][kt], aL2);
            aL3 = MFMA16(a1h, blo[1][kt], aL3);
            aL3 = MFMA16(a1l, bhi[1][kt], aL3);
        }

        // epilogue: + c[tgt] (hoisted regs) + ea rank-2, relu -> z_s[p] (read next iter)
#pragma unroll
        for (int r = 0; r < 4; ++r) {
            int r0 = quad * 4 + r, r1 = r0 + 16;
            float e00 = ea_s[0][r0], e01 = ea_s[1][r0];
            float e10 = ea_s[0][r1], e11 = ea_s[1][r1];
            z_s[p][r0][n0] = fmaxf(aH0[r] + aL0[r] * INV_LOSCALE + ctx00[r] + e00 * w256_0 + e01 * w257_0, 0.f);
            z_s[p][r0][n1] = fmaxf(aH1[r] + aL1[r] * INV_LOSCALE + ctx01[r] + e00 * w256_1 + e01 * w257_1, 0.f);
            z_s[p][r1][n0] = fmaxf(aH2[r] + aL2[r] * INV_LOSCALE + ctx10[r] + e10 * w256_0 + e11 * w257_0, 0.f);
            z_s[p][r1][n1] = fmaxf(aH3[r] + aL3[r] * INV_LOSCALE + ctx11[r] + e10 * w256_1 + e11 * w257_1, 0.f);
        }

        q_cur = q_nxt; q_nxt = q_tmp;
        p ^= 1;
    }

    // final deferred segsum for the last tile
    bar_lds();
    if (tid < 128) {
        int c = tid;
        int pp = p ^ 1;
        float run = z_s[pp][0][c];
        int tp = ts_s[pp][0];
        bool open0 = true;
#pragma unroll
        for (int r = 1; r < 32; ++r) {
            int t = ts_s[pp][r];
            float v = z_s[pp][r][c];
            if (t == tp) { run += v; }
            else {
                float* pz = zagg + (size_t)tp * HD + c;
                if (open0) atomicAdd(pz, run);
                else       *pz = run;
                run = v; tp = t; open0 = false;
            }
        }
        atomicAdd(zagg + (size_t)tp * HD + c, run);
    }
}

// ---------------- node update (persistent; R9-proven bar_lds + loop-top h/da/de hoist) ----------------
__global__ __launch_bounds__(256) void k_node(
    float* __restrict__ h,
    unsigned short* __restrict__ hhi, unsigned short* __restrict__ hlo,
    const float* __restrict__ za, const float* __restrict__ ze,
    const float* __restrict__ da, const float* __restrict__ de,
    const unsigned short* __restrict__ W2hi, const unsigned short* __restrict__ W2lo,
    const float* __restrict__ b2a, const float* __restrict__ b2e,
    const float* __restrict__ g, const float* __restrict__ bln,
    const unsigned short* __restrict__ cWhi, const unsigned short* __restrict__ cWlo,
    const float* __restrict__ cb)
{
    __shared__ __align__(16) unsigned short a_hi[16][264], a_lo[16][264];
    __shared__ float t1_s[16][132];
    __shared__ __align__(16) unsigned short u_hi[16][136], u_lo[16][136];
    __shared__ float g_s[HD], b_s[HD];
    int tid = threadIdx.x;
    int wave = tid >> 6, lane = tid & 63;
    int l16 = lane & 15, quad = lane >> 4;
    int nb0 = wave * 2;
    int n0 = nb0 * 16 + l16, n1 = n0 + 16;

    if (tid < HD) { g_s[tid] = g[tid]; b_s[tid] = bln[tid]; }

    // persistent weight fragments (W2 + cW in registers, once per block)
    f16x8 b2h[2][8], b2l[2][8], bch[2][4], bcl[2][4];
#pragma unroll
    for (int b = 0; b < 2; ++b) {
        int n = (nb0 + b) * 16 + l16;
        const unsigned short* p2h = W2hi + n * 256 + quad * 8;
        const unsigned short* p2l = W2lo + n * 256 + quad * 8;
#pragma unroll
        for (int kt = 0; kt < 8; ++kt) {
            b2h[b][kt] = *(const f16x8*)(p2h + kt * 32);
            b2l[b][kt] = *(const f16x8*)(p2l + kt * 32);
        }
        const unsigned short* pch = cWhi + n * 128 + quad * 8;
        const unsigned short* pcl = cWlo + n * 128 + quad * 8;
#pragma unroll
        for (int kt = 0; kt < 4; ++kt) {
            bch[b][kt] = *(const f16x8*)(pch + kt * 32);
            bcl[b][kt] = *(const f16x8*)(pcl + kt * 32);
        }
    }
    float vb2a0 = b2a[n0], vb2a1 = b2a[n1];
    float vb2e0 = b2e[n0], vb2e1 = b2e[n1];
    float vcb0 = cb[n0], vcb1 = cb[n1];

    int nd = tid >> 4, part = tid & 15;
    const float* zsel = (part < 8) ? za : ze;
    int pq = part & 7;

    int stride = gridDim.x;
    int grp = blockIdx.x;

    // prologue prefetch of za/ze for first group
    float4 zf0, zf1, zf2, zf3;
    {
        const float4* sp = (const float4*)(zsel + (size_t)(grp * 16 + nd) * HD + pq * 16);
        zf0 = sp[0]; zf1 = sp[1]; zf2 = sp[2]; zf3 = sp[3];
    }

    for (; grp < NGRP; grp += stride) {
        int base = grp * 16;

        // hoisted current-group h/da/de — oldest VMEM batch of this iteration
        float hp[8], dav[4], dev[4];
#pragma unroll
        for (int r = 0; r < 4; ++r) {
            const float* hb = h + (size_t)(base + quad * 4 + r) * HD;
            hp[2 * r]     = hb[n0];
            hp[2 * r + 1] = hb[n1];
            dav[r] = da[base + quad * 4 + r];
            dev[r] = de[base + quad * 4 + r];
        }
        __builtin_amdgcn_sched_barrier(0);  // pin: h/da/de issued before anything below

        bar_lds();                          // S0: prev-iter P1 done reading a_*

        // ---- P0: split prefetched za/ze -> LDS ----
        {
            union { unsigned short s[16]; uint4 q[2]; } Hv, Lv;
            float4 fa[4] = {zf0, zf1, zf2, zf3};
#pragma unroll
            for (int i = 0; i < 4; ++i) {
                split_hl(fa[i].x, Hv.s[4*i+0], Lv.s[4*i+0]);
                split_hl(fa[i].y, Hv.s[4*i+1], Lv.s[4*i+1]);
                split_hl(fa[i].z, Hv.s[4*i+2], Lv.s[4*i+2]);
                split_hl(fa[i].w, Hv.s[4*i+3], Lv.s[4*i+3]);
            }
            int ko = part * 16;
            *(uint4*)&a_hi[nd][ko] = Hv.q[0]; *(uint4*)&a_hi[nd][ko + 8] = Hv.q[1];
            *(uint4*)&a_lo[nd][ko] = Lv.q[0]; *(uint4*)&a_lo[nd][ko + 8] = Lv.q[1];
        }
        bar_lds();                          // S1: staged

        // issue next-group za/ze prefetch (rides across S2/S3/S0)
        {
            int gnx = grp + stride;
            int pfg = (gnx < NGRP) ? gnx : grp;   // clamped; tail values unused
            const float4* sp = (const float4*)(zsel + (size_t)(pfg * 16 + nd) * HD + pq * 16);
            zf0 = sp[0]; zf1 = sp[1]; zf2 = sp[2]; zf3 = sp[3];
        }

        // ---- P1: [za|ze] @ [W2a;W2e] (K=256); h/da/de from hoisted regs ----
        f32x4 acc0 = {0,0,0,0}, acc1 = {0,0,0,0}, accL0 = {0,0,0,0}, accL1 = {0,0,0,0};
#pragma unroll
        for (int kt = 0; kt < 8; ++kt) {
            f16x8 ah = *(const f16x8*)&a_hi[l16][kt * 32 + quad * 8];
            f16x8 al = *(const f16x8*)&a_lo[l16][kt * 32 + quad * 8];
            acc0  = MFMA16(ah, b2h[0][kt], acc0);
            acc1  = MFMA16(ah, b2h[1][kt], acc1);
            accL0 = MFMA16(ah, b2l[0][kt], accL0);
            accL1 = MFMA16(ah, b2l[1][kt], accL1);
            accL0 = MFMA16(al, b2h[0][kt], accL0);
            accL1 = MFMA16(al, b2h[1][kt], accL1);
        }
#pragma unroll
        for (int r = 0; r < 4; ++r) {
            int ndl = quad * 4 + r;
            t1_s[ndl][n0] = acc0[r] + accL0[r] * INV_LOSCALE + hp[2 * r]     + dav[r] * vb2a0 + dev[r] * vb2e0;
            t1_s[ndl][n1] = acc1[r] + accL1[r] * INV_LOSCALE + hp[2 * r + 1] + dav[r] * vb2a1 + dev[r] * vb2e1;
        }
        bar_lds();                          // S2: t1 ready

        // ---- P2: LayerNorm ----
        float v[8]; float s = 0.f, ss = 0.f;
#pragma unroll
        for (int i = 0; i < 8; ++i) { v[i] = t1_s[nd][part * 8 + i]; s += v[i]; ss += v[i] * v[i]; }
#pragma unroll
        for (int m = 1; m < 16; m <<= 1) { s += __shfl_xor(s, m); ss += __shfl_xor(ss, m); }
        float mu = s * (1.f / HD);
        float var = ss * (1.f / HD) - mu * mu;
        float inv = rsqrtf(var + 1e-5f);
        {
            union { unsigned short s[8]; uint4 q; } Hu, Lu;
#pragma unroll
            for (int i = 0; i < 8; ++i) {
                int c = part * 8 + i;
                float u = (v[i] - mu) * inv * g_s[c] + b_s[c];
                t1_s[nd][c] = u;
                split_hl(u, Hu.s[i], Lu.s[i]);
            }
            *(uint4*)&u_hi[nd][part * 8] = Hu.q;
            *(uint4*)&u_lo[nd][part * 8] = Lu.q;
        }
        bar_lds();                          // S3: u ready

        // ---- P3: comb MFMA (persistent bch/bcl) ----
        f32x4 c0 = {0,0,0,0}, c1 = {0,0,0,0}, cL0 = {0,0,0,0}, cL1 = {0,0,0,0};
#pragma unroll
        for (int kt = 0; kt < 4; ++kt) {
            f16x8 ah = *(const f16x8*)&u_hi[l16][kt * 32 + quad * 8];
            f16x8 al = *(const f16x8*)&u_lo[l16][kt * 32 + quad * 8];
            c0  = MFMA16(ah, bch[0][kt], c0);
            c1  = MFMA16(ah, bch[1][kt], c1);
            cL0 = MFMA16(ah, bcl[0][kt], cL0);
            cL1 = MFMA16(ah, bcl[1][kt], cL1);
            cL0 = MFMA16(al, bch[0][kt], cL0);
            cL1 = MFMA16(al, bch[1][kt], cL1);
        }
#pragma unroll
        for (int r = 0; r < 4; ++r) {
            int ndl = quad * 4 + r;
            int go = (base + ndl) * HD;
            float u0 = t1_s[ndl][n0], u1 = t1_s[ndl][n1];
            float r0 = fmaxf(c0[r] + cL0[r] * INV_LOSCALE + vcb0, 0.f);
            float r1 = fmaxf(c1[r] + cL1[r] * INV_LOSCALE + vcb1, 0.f);
            float o0 = u0 + r0, o1 = u1 + r1;
            h[go + n0] = o0; h[go + n1] = o1;
            unsigned short hv, lv;
            split_hl(o0, hv, lv); hhi[go + n0] = hv; hlo[go + n0] = lv;
            split_hl(o1, hv, lv); hhi[go + n1] = hv; hlo[go + n1] = lv;
        }
    }
}

extern "C" void kernel_launch(void* const* d_in, const int* in_sizes, int n_in,
                              void* d_out, int out_size, void* d_ws, size_t ws_size,
                              hipStream_t stream) {
    const float* x    = (const float*)d_in[0];
    const int*   a_ei = (const int*)d_in[1];
    const float* a_ea = (const float*)d_in[2];
    const int*   e_ei = (const int*)d_in[3];
    const float* e_ea = (const float*)d_in[4];
    const float* W_in = (const float*)d_in[5];
    const float* b_in = (const float*)d_in[6];
    const float* aW1  = (const float*)d_in[7];
    const float* ab1  = (const float*)d_in[8];
    const float* aW2  = (const float*)d_in[9];
    const float* ab2  = (const float*)d_in[10];
    const float* eW1  = (const float*)d_in[11];
    const float* eb1  = (const float*)d_in[12];
    const float* eW2  = (const float*)d_in[13];
    const float* eb2  = (const float*)d_in[14];
    const float* ln_g = (const float*)d_in[15];
    const float* ln_b = (const float*)d_in[16];
    const float* cW   = (const float*)d_in[17];
    const float* cb   = (const float*)d_in[18];
    float* h = (float*)d_out;

    // ---- workspace layout, total ~226 MB ----
    char* ws = (char*)d_ws;
    int4* es = (int4*)ws;                        ws += (size_t)2 * EE * 16;     // 19.2 MB
    unsigned short* hhi = (unsigned short*)ws;   ws += (size_t)NN * HD * 2;     // 25.6 MB
    unsigned short* hlo = (unsigned short*)ws;   ws += (size_t)NN * HD * 2;     // 25.6 MB
    float* zagg_a = (float*)ws;                  ws += (size_t)NN * HD * 4;     // 51.2 MB
    float* zagg_e = (float*)ws;                  ws += (size_t)NN * HD * 4;     // 51.2 MB
    float* ctx = (float*)ws;                     ws += (size_t)NN * HD * 4;     // 51.2 MB (shared per graph)
    unsigned short* W1thi = (unsigned short*)ws; ws += (size_t)4 * HD * K1 * 2;
    unsigned short* W1tlo = (unsigned short*)ws; ws += (size_t)4 * HD * K1 * 2;
    unsigned short* W2thi = (unsigned short*)ws; ws += (size_t)2 * HD * 256 * 2;
    unsigned short* W2tlo = (unsigned short*)ws; ws += (size_t)2 * HD * 256 * 2;
    unsigned short* cWthi = (unsigned short*)ws; ws += (size_t)2 * HD * HD * 2;
    unsigned short* cWtlo = (unsigned short*)ws; ws += (size_t)2 * HD * HD * 2;
    float* da = (float*)ws;                      ws += (size_t)NN * 4;
    float* de = (float*)ws;                      ws += (size_t)NN * 4;
    // CSR-build scratch aliased into ctx (dead before first k_ctx writes ctx)
    int* cnt = (int*)ctx;
    int* cur = cnt + 2 * NN;
    int* bsum = cur + 2 * NN;
    int* bpre = bsum + 2 * SCB;

    k_input_proj<<<NN / 16, 256, 0, stream>>>(x, W_in, b_in, h, hhi, hlo);

    // CSR build (once per launch; reused by both layers)
    hipMemsetAsync(cnt, 0, (size_t)2 * NN * 4, stream);
    dim3 ge((EE + 255) / 256, 2);
    k_hist<<<ge, 256, 0, stream>>>(a_ei, e_ei, cnt);
    dim3 gs(SCB, 2);
    k_scanA<<<gs, 256, 0, stream>>>(cnt, bsum);
    k_scanB<<<1, 64, 0, stream>>>(bsum, bpre);
    k_scanC<<<gs, 256, 0, stream>>>(cnt, bpre, cur, da, de);
    k_scatter<<<ge, 256, 0, stream>>>(a_ei, a_ea, e_ei, e_ea, cur, es);

    k_prep_all<<<896, 256, 0, stream>>>(aW1, eW1, aW2, eW2, cW,
                                        W1thi, W1tlo, W2thi, W2tlo, cWthi, cWtlo);

    const int W1SZ = (2 * HD + 2) * HD;
    for (int l = 0; l < 2; ++l) {
        hipMemsetAsync(zagg_a, 0, (size_t)2 * NN * HD * 4, stream);  // zagg_a + zagg_e adjacent
        k_ctx<<<1024, 256, 0, stream>>>(hhi, hlo,
            W1thi + (0 + l) * HD * K1, W1tlo + (0 + l) * HD * K1, ab1 + l * HD, ctx);
        k_edge<<<2048, 256, 0, stream>>>(hhi, hlo, es,
            W1thi + (0 + l) * HD * K1, W1tlo + (0 + l) * HD * K1,
            aW1 + (size_t)l * W1SZ, ctx, zagg_a);
        k_ctx<<<1024, 256, 0, stream>>>(hhi, hlo,
            W1thi + (2 + l) * HD * K1, W1tlo + (2 + l) * HD * K1, eb1 + l * HD, ctx);
        k_edge<<<2048, 256, 0, stream>>>(hhi, hlo, es + (size_t)EE,
            W1thi + (2 + l) * HD * K1, W1tlo + (2 + l) * HD * K1,
            eW1 + (size_t)l * W1SZ, ctx, zagg_e);
        k_node<<<512, 256, 0, stream>>>(h, hhi, hlo, zagg_a, zagg_e, da, de,
            W2thi + l * HD * 256, W2tlo + l * HD * 256, ab2 + l * HD, eb2 + l * HD,
            ln_g + l * HD, ln_b + l * HD,
            cWthi + l * HD * HD, cWtlo + l * HD * HD, cb + l * HD);
    }
}

// Round 12
// 1146.083 us; speedup vs baseline: 1.5401x; 1.1640x over previous
//
#include <hip/hip_runtime.h>

#define NN 100000
#define EE 600000
#define FIN 39
#define HD 128
#define K1 256          // W1t layout K (k<128 = target half, k>=128 = source half)
#define NT32 (EE / 32)  // 18750 edge tiles of 32
#define NGRP (NN / 16)  // 6250 node groups of 16
#define LOSCALE 4096.0f
#define INV_LOSCALE (1.0f / 4096.0f)
#define SCB 98          // scan blocks per graph: 98*1024 >= NN

typedef _Float16 f16x8 __attribute__((ext_vector_type(8)));
typedef __attribute__((ext_vector_type(4))) float f32x4;

#define MFMA16(a, b, c) __builtin_amdgcn_mfma_f32_16x16x32_f16((a), (b), (c), 0, 0, 0)

__device__ __forceinline__ void split_hl(float x, unsigned short& hi, unsigned short& lo) {
    union { _Float16 h; unsigned short u; } a, b;
    a.h = (_Float16)x;
    float r = (x - (float)a.h) * LOSCALE;   // scaled residual stays fp16-normal
    b.h = (_Float16)r;
    hi = a.u; lo = b.u;
}

// LDS-only barrier: drains LDS ops (cross-wave staging visibility) but leaves VMEM
// loads in flight. __syncthreads() would emit s_waitcnt vmcnt(0) before s_barrier,
// force-draining the gather prefetch every phase (the R2..R6 hidden serializer).
__device__ __forceinline__ void bar_lds() {
    asm volatile("s_waitcnt lgkmcnt(0)" ::: "memory");
    __builtin_amdgcn_s_barrier();
}

// ---------------- input projection: h = relu(x @ W_in + b_in), fp32; emit hi/lo ----------------
__global__ __launch_bounds__(256) void k_input_proj(
    const float* __restrict__ x, const float* __restrict__ Wi,
    const float* __restrict__ bi, float* __restrict__ h,
    unsigned short* __restrict__ hhi, unsigned short* __restrict__ hlo)
{
    __shared__ float Ws[FIN * HD];
    __shared__ float xs[16][FIN + 1];
    int tid = threadIdx.x;
    for (int i = tid; i < FIN * HD; i += 256) Ws[i] = Wi[i];
    int base = blockIdx.x * 16;
    for (int i = tid; i < 16 * FIN; i += 256) {
        int nd = i / FIN, k = i - nd * FIN;
        xs[nd][k] = x[(size_t)(base + nd) * FIN + k];
    }
    __syncthreads();
    int j = tid & 127, slot = tid >> 7;
    float bj = bi[j];
    for (int r = 0; r < 8; ++r) {
        int nd = slot * 8 + r;
        float acc = bj;
#pragma unroll
        for (int k = 0; k < FIN; ++k) acc += xs[nd][k] * Ws[k * HD + j];
        acc = fmaxf(acc, 0.f);
        int o = (base + nd) * HD + j;
        h[o] = acc;
        unsigned short hv, lv; split_hl(acc, hv, lv);
        hhi[o] = hv; hlo[o] = lv;
    }
}

// ---------------- CSR build ----------------
__global__ __launch_bounds__(256) void k_hist(const int* __restrict__ a_ei, const int* __restrict__ e_ei,
                                              int* __restrict__ cnt) {
    int g = blockIdx.y;
    int gid = blockIdx.x * 256 + threadIdx.x;
    if (gid >= EE) return;
    const int* ei = g ? e_ei : a_ei;
    atomicAdd(&cnt[g * NN + ei[EE + gid]], 1);
}

__global__ __launch_bounds__(256) void k_scanA(const int* __restrict__ cnt, int* __restrict__ bsum) {
    int g = blockIdx.y, b = blockIdx.x, tid = threadIdx.x;
    int base = b * 1024 + tid * 4;
    int s = 0;
#pragma unroll
    for (int j = 0; j < 4; ++j) {
        int i = base + j;
        if (i < NN) s += cnt[g * NN + i];
    }
    __shared__ int lds[256];
    lds[tid] = s; __syncthreads();
    for (int o = 128; o > 0; o >>= 1) {
        if (tid < o) lds[tid] += lds[tid + o];
        __syncthreads();
    }
    if (tid == 0) bsum[g * SCB + b] = lds[0];
}

__global__ __launch_bounds__(64) void k_scanB(const int* __restrict__ bsum, int* __restrict__ bpre) {
    int tid = threadIdx.x;
    if (tid < 2) {
        int run = 0;
        for (int b = 0; b < SCB; ++b) { bpre[tid * SCB + b] = run; run += bsum[tid * SCB + b]; }
    }
}

__global__ __launch_bounds__(256) void k_scanC(const int* __restrict__ cnt, const int* __restrict__ bpre,
                                               int* __restrict__ cur,
                                               float* __restrict__ da, float* __restrict__ de) {
    int g = blockIdx.y, b = blockIdx.x, tid = threadIdx.x;
    float* dg = g ? de : da;
    int base = b * 1024 + tid * 4;
    int c[4]; int ts = 0;
#pragma unroll
    for (int j = 0; j < 4; ++j) {
        int i = base + j;
        c[j] = (i < NN) ? cnt[g * NN + i] : 0;
        ts += c[j];
    }
    __shared__ int lds[256];
    lds[tid] = ts; __syncthreads();
    for (int o = 1; o < 256; o <<= 1) {
        int v = (tid >= o) ? lds[tid - o] : 0;
        __syncthreads();
        lds[tid] += v;
        __syncthreads();
    }
    int run = lds[tid] - ts + bpre[g * SCB + b];
#pragma unroll
    for (int j = 0; j < 4; ++j) {
        int i = base + j;
        if (i < NN) { cur[g * NN + i] = run; dg[i] = (float)c[j]; run += c[j]; }
    }
}

__global__ __launch_bounds__(256) void k_scatter(
    const int* __restrict__ a_ei, const float* __restrict__ a_ea,
    const int* __restrict__ e_ei, const float* __restrict__ e_ea,
    int* __restrict__ cur, int4* __restrict__ es) {
    int g = blockIdx.y;
    int gid = blockIdx.x * 256 + threadIdx.x;
    if (gid >= EE) return;
    const int* ei = g ? e_ei : a_ei;
    const float* ea = g ? e_ea : a_ea;
    int src = ei[gid], tgt = ei[EE + gid];
    int slot = atomicAdd(&cur[g * NN + tgt], 1);
    es[(size_t)g * EE + slot] = make_int4(src, tgt,
        __float_as_int(ea[2 * gid]), __float_as_int(ea[2 * gid + 1]));
}

// ---------------- fused weight prep (hi/lo, n-major transposed) ----------------
__global__ __launch_bounds__(256) void k_prep_all(
    const float* __restrict__ aW1, const float* __restrict__ eW1,
    const float* __restrict__ aW2, const float* __restrict__ eW2,
    const float* __restrict__ cW,
    unsigned short* __restrict__ W1thi, unsigned short* __restrict__ W1tlo,
    unsigned short* __restrict__ W2thi, unsigned short* __restrict__ W2tlo,
    unsigned short* __restrict__ cWthi, unsigned short* __restrict__ cWtlo) {
    int i = blockIdx.x * 256 + threadIdx.x;
    unsigned short hv, lv;
    if (i < 131072) {                       // W1: 4 x [128n][256k]
        int s = i >> 15, r = i & 32767;
        const float* W = ((s < 2) ? aW1 : eW1) + (size_t)(s & 1) * 258 * HD;
        int n = r >> 8, k = r & 255;
        split_hl(W[k * HD + n], hv, lv);
        W1thi[i] = hv; W1tlo[i] = lv;
    } else if (i < 196608) {                // W2: 2 x [128n][256k] ([W2a;W2e])
        int j = i - 131072;
        int l = j >> 15, r = j & 32767;
        int n = r >> 8, k = r & 255;
        float v = (k < HD) ? aW2[(size_t)l * HD * HD + k * HD + n]
                           : eW2[(size_t)l * HD * HD + (k - HD) * HD + n];
        split_hl(v, hv, lv);
        W2thi[j] = hv; W2tlo[j] = lv;
    } else if (i < 229376) {                // cW: 2 x [128n][128k]
        int j = i - 196608;
        int l = j >> 14, r = j & 16383;
        int n = r >> 7, k = r & 127;
        split_hl(cW[(size_t)l * HD * HD + k * HD + n], hv, lv);
        cWthi[j] = hv; cWtlo[j] = lv;
    }
}

// ---------------- target context (persistent; R12: bar_lds so hi/lo prefetch rides barriers) ----------------
// c[t][n] = sum_k<128 h_t[k] W1[k][n] + b1[n]
// Barriers only guard a_hi/a_lo staging (LDS) — bar_lds preserves that; the prefetch issued
// after "staged" now survives the MFMA + cc-stores + loop-top barrier and is waited only at
// the LDS-write dependency (vmcnt >= 8 stores, all younger). cc crosses a kernel boundary.
__global__ __launch_bounds__(256) void k_ctx(
    const unsigned short* __restrict__ hhi, const unsigned short* __restrict__ hlo,
    const unsigned short* __restrict__ Whi, const unsigned short* __restrict__ Wlo,
    const float* __restrict__ b1, float* __restrict__ cc)
{
    __shared__ __align__(16) unsigned short a_hi[16 * 128], a_lo[16 * 128];
    int tid = threadIdx.x;
    int wave = tid >> 6, lane = tid & 63;
    int l16 = lane & 15, quad = lane >> 4;
    int n0 = wave * 32 + l16, n1 = n0 + 16;

    // persistent B fragments (loaded once per block)
    f16x8 bh[2][4], bl[2][4];
#pragma unroll
    for (int b = 0; b < 2; ++b) {
        int n = wave * 32 + b * 16 + l16;
        const unsigned short* ph = Whi + n * K1 + quad * 8;   // target half: k 0..127
        const unsigned short* pl = Wlo + n * K1 + quad * 8;
#pragma unroll
        for (int kt = 0; kt < 4; ++kt) {
            bh[b][kt] = *(const f16x8*)(ph + kt * 32);
            bl[b][kt] = *(const f16x8*)(pl + kt * 32);
        }
    }
    float vb0 = b1[n0], vb1 = b1[n1];

    int nd = tid >> 4, part = tid & 15;
    int pm = part & 7;
    const unsigned short* hsel = (part < 8) ? hhi : hlo;
    unsigned short* msel = ((part < 8) ? a_hi : a_lo) + nd * 128;
    int c0i = (2 * pm) ^ nd, c1i = (2 * pm + 1) ^ nd;

    int stride = gridDim.x;
    int grp = blockIdx.x;

    // prologue prefetch for first group
    uint4 v0, v1;
    {
        const uint4* gpp = (const uint4*)(hsel + (size_t)(grp * 16 + nd) * HD + pm * 16);
        v0 = gpp[0]; v1 = gpp[1];
    }

    for (; grp < NGRP; grp += stride) {
        bar_lds();                          // prev-iter MFMA readers done with a_hi/a_lo
        *(uint4*)(msel + c0i * 8) = v0;
        *(uint4*)(msel + c1i * 8) = v1;
        bar_lds();                          // staged

        // issue next-group prefetch (rides across MFMA + cc stores + loop-top barrier)
        {
            int gnx = grp + stride;
            int pfg = (gnx < NGRP) ? gnx : grp;
            const uint4* gpp = (const uint4*)(hsel + (size_t)(pfg * 16 + nd) * HD + pm * 16);
            v0 = gpp[0]; v1 = gpp[1];
        }

        f32x4 h0 = {0,0,0,0}, h1 = {0,0,0,0}, L0 = {0,0,0,0}, L1 = {0,0,0,0};
#pragma unroll
        for (int kt = 0; kt < 4; ++kt) {
            int ch = ((kt * 4 + quad) ^ l16) * 8;
            f16x8 ah = *(const f16x8*)(a_hi + l16 * 128 + ch);
            f16x8 al = *(const f16x8*)(a_lo + l16 * 128 + ch);
            h0 = MFMA16(ah, bh[0][kt], h0);
            h1 = MFMA16(ah, bh[1][kt], h1);
            L0 = MFMA16(ah, bl[0][kt], L0);
            L0 = MFMA16(al, bh[0][kt], L0);
            L1 = MFMA16(ah, bl[1][kt], L1);
            L1 = MFMA16(al, bh[1][kt], L1);
        }
        int base = grp * 16;
#pragma unroll
        for (int r = 0; r < 4; ++r) {
            int rr = quad * 4 + r;
            float* cp = cc + (size_t)(base + rr) * HD;
            cp[n0] = h0[r] + L0[r] * INV_LOSCALE + vb0;
            cp[n1] = h1[r] + L1[r] * INV_LOSCALE + vb1;
        }
    }
}

// ---------------- edge conv (R9-exact: bar_lds + ctx hoist, dynamic segsum at tail) ----------------
__global__ __launch_bounds__(256, 3) void k_edge(
    const unsigned short* __restrict__ hhi, const unsigned short* __restrict__ hlo,
    const int4* __restrict__ es,          // sorted by target: (src,tgt,ea0,ea1)
    const unsigned short* __restrict__ Whi, const unsigned short* __restrict__ Wlo, // [128][256]
    const float* __restrict__ W1full,     // rows 256/257 for ea
    const float* __restrict__ cctx,       // [node][128]: tgt half + b1
    float* __restrict__ zagg)
{
    __shared__ __align__(16) unsigned short m_hi[32 * 128];
    __shared__ __align__(16) unsigned short m_lo[32 * 128];
    __shared__ float z_s[32][132];
    __shared__ int   ts_s[32];
    __shared__ float ea_s[2][32];

    int tid = threadIdx.x;
    int wave = tid >> 6, lane = tid & 63;
    int l16 = lane & 15, quad = lane >> 4;
    int n0 = wave * 32 + l16, n1 = n0 + 16;

    // persistent B fragments: source half of W1 (k = 128..255)
    f16x8 bhi[2][4], blo[2][4];
#pragma unroll
    for (int b = 0; b < 2; ++b) {
        int n = wave * 32 + b * 16 + l16;
        const unsigned short* ph = Whi + n * K1 + 128 + quad * 8;
        const unsigned short* pl = Wlo + n * K1 + 128 + quad * 8;
#pragma unroll
        for (int kt = 0; kt < 4; ++kt) {
            bhi[b][kt] = *(const f16x8*)(ph + kt * 32);
            blo[b][kt] = *(const f16x8*)(pl + kt * 32);
        }
    }
    float w256_0 = W1full[256 * HD + n0], w257_0 = W1full[257 * HD + n0];
    float w256_1 = W1full[256 * HD + n1], w257_1 = W1full[257 * HD + n1];

    int row = tid >> 3, part = tid & 7;   // 32 rows x 8 parts (64B each)
    int pm = part & 3;
    const unsigned short* hsel = (part < 4) ? hhi : hlo;
    unsigned short* msel = ((part < 4) ? m_hi : m_lo) + row * 128;
    int sw = row & 15;

    int stride = gridDim.x;
    int tile = blockIdx.x;

    // prologue: q_cur(tile), gather G(tile), q_nxt(tile+stride)
    int4 q_cur = es[tile * 32 + row];
    uint4 G0, G1, G2, G3;
    {
        const uint4* gp = (const uint4*)(hsel + (size_t)q_cur.x * HD + pm * 32);
        G0 = gp[0]; G1 = gp[1]; G2 = gp[2]; G3 = gp[3];
    }
    int tn = tile + stride;
    int4 q_nxt = es[(tn < NT32 ? tn : tile) * 32 + row];

    for (; tile < NT32; tile += stride) {
        bar_lds();                          // A: prev-iter segsum LDS reads done
        if (part == 0) {
            ts_s[row] = q_cur.y;
            ea_s[0][row] = __int_as_float(q_cur.z);
            ea_s[1][row] = __int_as_float(q_cur.w);
        }
        {
            int c0 = (pm * 4 + 0) ^ sw, c1 = (pm * 4 + 1) ^ sw;
            int c2 = (pm * 4 + 2) ^ sw, c3 = (pm * 4 + 3) ^ sw;
            *(uint4*)(msel + c0 * 8) = G0;
            *(uint4*)(msel + c1 * 8) = G1;
            *(uint4*)(msel + c2 * 8) = G2;
            *(uint4*)(msel + c3 * 8) = G3;
        }
        bar_lds();                          // B: staging visible to all waves

        // hoisted ctx loads — oldest VMEM batch of this iteration (ts_s valid post-B)
        float ctx00[4], ctx01[4], ctx10[4], ctx11[4];
#pragma unroll
        for (int r = 0; r < 4; ++r) {
            int r0 = quad * 4 + r, r1 = r0 + 16;
            const float* cp0 = cctx + (size_t)ts_s[r0] * HD;
            const float* cp1 = cctx + (size_t)ts_s[r1] * HD;
            ctx00[r] = cp0[n0]; ctx01[r] = cp0[n1];
            ctx10[r] = cp1[n0]; ctx11[r] = cp1[n1];
        }
        __builtin_amdgcn_sched_barrier(0);  // pin: ctx issued before gather/es below

        // gather for next tile + es two ahead — ride across C/A, waited at next staging
        {
            const uint4* gp = (const uint4*)(hsel + (size_t)q_nxt.x * HD + pm * 32);
            G0 = gp[0]; G1 = gp[1]; G2 = gp[2]; G3 = gp[3];
        }
        int t2 = tile + 2 * stride;
        int4 q_tmp = es[(t2 < NT32 ? t2 : tile) * 32 + row];

        f32x4 aH0 = {0,0,0,0}, aH1 = {0,0,0,0}, aH2 = {0,0,0,0}, aH3 = {0,0,0,0};
        f32x4 aL0 = {0,0,0,0}, aL1 = {0,0,0,0}, aL2 = {0,0,0,0}, aL3 = {0,0,0,0};
#pragma unroll
        for (int kt = 0; kt < 4; ++kt) {
            int ch = ((kt * 4 + quad) ^ l16) * 8;
            f16x8 a0h = *(const f16x8*)(m_hi + l16 * 128 + ch);
            f16x8 a0l = *(const f16x8*)(m_lo + l16 * 128 + ch);
            f16x8 a1h = *(const f16x8*)(m_hi + (l16 + 16) * 128 + ch);
            f16x8 a1l = *(const f16x8*)(m_lo + (l16 + 16) * 128 + ch);
            aH0 = MFMA16(a0h, bhi[0][kt], aH0);
            aH1 = MFMA16(a0h, bhi[1][kt], aH1);
            aH2 = MFMA16(a1h, bhi[0][kt], aH2);
            aH3 = MFMA16(a1h, bhi[1][kt], aH3);
            aL0 = MFMA16(a0h, blo[0][kt], aL0);
            aL0 = MFMA16(a0l, bhi[0][kt], aL0);
            aL1 = MFMA16(a0h, blo[1][kt], aL1);
            aL1 = MFMA16(a0l, bhi[1][kt], aL1);
            aL2 = MFMA16(a1h, blo[0][kt], aL2);
            aL2 = MFMA16(a1l, bhi[0][kt], aL2);
            aL3 = MFMA16(a1h, blo[1][kt], aL3);
            aL3 = MFMA16(a1l, bhi[1][kt], aL3);
        }

        // epilogue: + c[tgt] (hoisted regs) + ea rank-2, relu -> z_s
#pragma unroll
        for (int r = 0; r < 4; ++r) {
            int r0 = quad * 4 + r, r1 = r0 + 16;
            float e00 = ea_s[0][r0], e01 = ea_s[1][r0];
            float e10 = ea_s[0][r1], e11 = ea_s[1][r1];
            z_s[r0][n0] = fmaxf(aH0[r] + aL0[r] * INV_LOSCALE + ctx00[r] + e00 * w256_0 + e01 * w257_0, 0.f);
            z_s[r0][n1] = fmaxf(aH1[r] + aL1[r] * INV_LOSCALE + ctx01[r] + e00 * w256_1 + e01 * w257_1, 0.f);
            z_s[r1][n0] = fmaxf(aH2[r] + aL2[r] * INV_LOSCALE + ctx10[r] + e10 * w256_0 + e11 * w257_0, 0.f);
            z_s[r1][n1] = fmaxf(aH3[r] + aL3[r] * INV_LOSCALE + ctx11[r] + e10 * w256_1 + e11 * w257_1, 0.f);
        }
        bar_lds();                          // C: z_s visible

        // segmented sum over 32 sorted rows
        if (tid < 128) {
            int c = tid;
            float run = z_s[0][c];
            int tp = ts_s[0];
            bool open0 = true;
#pragma unroll
            for (int r = 1; r < 32; ++r) {
                int t = ts_s[r];
                float v = z_s[r][c];
                if (t == tp) { run += v; }
                else {
                    float* p = zagg + (size_t)tp * HD + c;
                    if (open0) atomicAdd(p, run);
                    else       *p = run;
                    run = v; tp = t; open0 = false;
                }
            }
            atomicAdd(zagg + (size_t)tp * HD + c, run);
        }

        q_cur = q_nxt; q_nxt = q_tmp;
    }
}

// ---------------- node update (persistent; R9-proven bar_lds + loop-top h/da/de hoist) ----------------
__global__ __launch_bounds__(256) void k_node(
    float* __restrict__ h,
    unsigned short* __restrict__ hhi, unsigned short* __restrict__ hlo,
    const float* __restrict__ za, const float* __restrict__ ze,
    const float* __restrict__ da, const float* __restrict__ de,
    const unsigned short* __restrict__ W2hi, const unsigned short* __restrict__ W2lo,
    const float* __restrict__ b2a, const float* __restrict__ b2e,
    const float* __restrict__ g, const float* __restrict__ bln,
    const unsigned short* __restrict__ cWhi, const unsigned short* __restrict__ cWlo,
    const float* __restrict__ cb)
{
    __shared__ __align__(16) unsigned short a_hi[16][264], a_lo[16][264];
    __shared__ float t1_s[16][132];
    __shared__ __align__(16) unsigned short u_hi[16][136], u_lo[16][136];
    __shared__ float g_s[HD], b_s[HD];
    int tid = threadIdx.x;
    int wave = tid >> 6, lane = tid & 63;
    int l16 = lane & 15, quad = lane >> 4;
    int nb0 = wave * 2;
    int n0 = nb0 * 16 + l16, n1 = n0 + 16;

    if (tid < HD) { g_s[tid] = g[tid]; b_s[tid] = bln[tid]; }

    // persistent weight fragments (W2 + cW in registers, once per block)
    f16x8 b2h[2][8], b2l[2][8], bch[2][4], bcl[2][4];
#pragma unroll
    for (int b = 0; b < 2; ++b) {
        int n = (nb0 + b) * 16 + l16;
        const unsigned short* p2h = W2hi + n * 256 + quad * 8;
        const unsigned short* p2l = W2lo + n * 256 + quad * 8;
#pragma unroll
        for (int kt = 0; kt < 8; ++kt) {
            b2h[b][kt] = *(const f16x8*)(p2h + kt * 32);
            b2l[b][kt] = *(const f16x8*)(p2l + kt * 32);
        }
        const unsigned short* pch = cWhi + n * 128 + quad * 8;
        const unsigned short* pcl = cWlo + n * 128 + quad * 8;
#pragma unroll
        for (int kt = 0; kt < 4; ++kt) {
            bch[b][kt] = *(const f16x8*)(pch + kt * 32);
            bcl[b][kt] = *(const f16x8*)(pcl + kt * 32);
        }
    }
    float vb2a0 = b2a[n0], vb2a1 = b2a[n1];
    float vb2e0 = b2e[n0], vb2e1 = b2e[n1];
    float vcb0 = cb[n0], vcb1 = cb[n1];

    int nd = tid >> 4, part = tid & 15;
    const float* zsel = (part < 8) ? za : ze;
    int pq = part & 7;

    int stride = gridDim.x;
    int grp = blockIdx.x;

    // prologue prefetch of za/ze for first group
    float4 zf0, zf1, zf2, zf3;
    {
        const float4* sp = (const float4*)(zsel + (size_t)(grp * 16 + nd) * HD + pq * 16);
        zf0 = sp[0]; zf1 = sp[1]; zf2 = sp[2]; zf3 = sp[3];
    }

    for (; grp < NGRP; grp += stride) {
        int base = grp * 16;

        // hoisted current-group h/da/de — oldest VMEM batch of this iteration
        float hp[8], dav[4], dev[4];
#pragma unroll
        for (int r = 0; r < 4; ++r) {
            const float* hb = h + (size_t)(base + quad * 4 + r) * HD;
            hp[2 * r]     = hb[n0];
            hp[2 * r + 1] = hb[n1];
            dav[r] = da[base + quad * 4 + r];
            dev[r] = de[base + quad * 4 + r];
        }
        __builtin_amdgcn_sched_barrier(0);  // pin: h/da/de issued before anything below

        bar_lds();                          // S0: prev-iter P1 done reading a_*

        // ---- P0: split prefetched za/ze -> LDS ----
        {
            union { unsigned short s[16]; uint4 q[2]; } Hv, Lv;
            float4 fa[4] = {zf0, zf1, zf2, zf3};
#pragma unroll
            for (int i = 0; i < 4; ++i) {
                split_hl(fa[i].x, Hv.s[4*i+0], Lv.s[4*i+0]);
                split_hl(fa[i].y, Hv.s[4*i+1], Lv.s[4*i+1]);
                split_hl(fa[i].z, Hv.s[4*i+2], Lv.s[4*i+2]);
                split_hl(fa[i].w, Hv.s[4*i+3], Lv.s[4*i+3]);
            }
            int ko = part * 16;
            *(uint4*)&a_hi[nd][ko] = Hv.q[0]; *(uint4*)&a_hi[nd][ko + 8] = Hv.q[1];
            *(uint4*)&a_lo[nd][ko] = Lv.q[0]; *(uint4*)&a_lo[nd][ko + 8] = Lv.q[1];
        }
        bar_lds();                          // S1: staged

        // issue next-group za/ze prefetch (rides across S2/S3/S0)
        {
            int gnx = grp + stride;
            int pfg = (gnx < NGRP) ? gnx : grp;   // clamped; tail values unused
            const float4* sp = (const float4*)(zsel + (size_t)(pfg * 16 + nd) * HD + pq * 16);
            zf0 = sp[0]; zf1 = sp[1]; zf2 = sp[2]; zf3 = sp[3];
        }

        // ---- P1: [za|ze] @ [W2a;W2e] (K=256); h/da/de from hoisted regs ----
        f32x4 acc0 = {0,0,0,0}, acc1 = {0,0,0,0}, accL0 = {0,0,0,0}, accL1 = {0,0,0,0};
#pragma unroll
        for (int kt = 0; kt < 8; ++kt) {
            f16x8 ah = *(const f16x8*)&a_hi[l16][kt * 32 + quad * 8];
            f16x8 al = *(const f16x8*)&a_lo[l16][kt * 32 + quad * 8];
            acc0  = MFMA16(ah, b2h[0][kt], acc0);
            acc1  = MFMA16(ah, b2h[1][kt], acc1);
            accL0 = MFMA16(ah, b2l[0][kt], accL0);
            accL1 = MFMA16(ah, b2l[1][kt], accL1);
            accL0 = MFMA16(al, b2h[0][kt], accL0);
            accL1 = MFMA16(al, b2h[1][kt], accL1);
        }
#pragma unroll
        for (int r = 0; r < 4; ++r) {
            int ndl = quad * 4 + r;
            t1_s[ndl][n0] = acc0[r] + accL0[r] * INV_LOSCALE + hp[2 * r]     + dav[r] * vb2a0 + dev[r] * vb2e0;
            t1_s[ndl][n1] = acc1[r] + accL1[r] * INV_LOSCALE + hp[2 * r + 1] + dav[r] * vb2a1 + dev[r] * vb2e1;
        }
        bar_lds();                          // S2: t1 ready

        // ---- P2: LayerNorm ----
        float v[8]; float s = 0.f, ss = 0.f;
#pragma unroll
        for (int i = 0; i < 8; ++i) { v[i] = t1_s[nd][part * 8 + i]; s += v[i]; ss += v[i] * v[i]; }
#pragma unroll
        for (int m = 1; m < 16; m <<= 1) { s += __shfl_xor(s, m); ss += __shfl_xor(ss, m); }
        float mu = s * (1.f / HD);
        float var = ss * (1.f / HD) - mu * mu;
        float inv = rsqrtf(var + 1e-5f);
        {
            union { unsigned short s[8]; uint4 q; } Hu, Lu;
#pragma unroll
            for (int i = 0; i < 8; ++i) {
                int c = part * 8 + i;
                float u = (v[i] - mu) * inv * g_s[c] + b_s[c];
                t1_s[nd][c] = u;
                split_hl(u, Hu.s[i], Lu.s[i]);
            }
            *(uint4*)&u_hi[nd][part * 8] = Hu.q;
            *(uint4*)&u_lo[nd][part * 8] = Lu.q;
        }
        bar_lds();                          // S3: u ready

        // ---- P3: comb MFMA (persistent bch/bcl) ----
        f32x4 c0 = {0,0,0,0}, c1 = {0,0,0,0}, cL0 = {0,0,0,0}, cL1 = {0,0,0,0};
#pragma unroll
        for (int kt = 0; kt < 4; ++kt) {
            f16x8 ah = *(const f16x8*)&u_hi[l16][kt * 32 + quad * 8];
            f16x8 al = *(const f16x8*)&u_lo[l16][kt * 32 + quad * 8];
            c0  = MFMA16(ah, bch[0][kt], c0);
            c1  = MFMA16(ah, bch[1][kt], c1);
            cL0 = MFMA16(ah, bcl[0][kt], cL0);
            cL1 = MFMA16(ah, bcl[1][kt], cL1);
            cL0 = MFMA16(al, bch[0][kt], cL0);
            cL1 = MFMA16(al, bch[1][kt], cL1);
        }
#pragma unroll
        for (int r = 0; r < 4; ++r) {
            int ndl = quad * 4 + r;
            int go = (base + ndl) * HD;
            float u0 = t1_s[ndl][n0], u1 = t1_s[ndl][n1];
            float r0 = fmaxf(c0[r] + cL0[r] * INV_LOSCALE + vcb0, 0.f);
            float r1 = fmaxf(c1[r] + cL1[r] * INV_LOSCALE + vcb1, 0.f);
            float o0 = u0 + r0, o1 = u1 + r1;
            h[go + n0] = o0; h[go + n1] = o1;
            unsigned short hv, lv;
            split_hl(o0, hv, lv); hhi[go + n0] = hv; hlo[go + n0] = lv;
            split_hl(o1, hv, lv); hhi[go + n1] = hv; hlo[go + n1] = lv;
        }
    }
}

extern "C" void kernel_launch(void* const* d_in, const int* in_sizes, int n_in,
                              void* d_out, int out_size, void* d_ws, size_t ws_size,
                              hipStream_t stream) {
    const float* x    = (const float*)d_in[0];
    const int*   a_ei = (const int*)d_in[1];
    const float* a_ea = (const float*)d_in[2];
    const int*   e_ei = (const int*)d_in[3];
    const float* e_ea = (const float*)d_in[4];
    const float* W_in = (const float*)d_in[5];
    const float* b_in = (const float*)d_in[6];
    const float* aW1  = (const float*)d_in[7];
    const float* ab1  = (const float*)d_in[8];
    const float* aW2  = (const float*)d_in[9];
    const float* ab2  = (const float*)d_in[10];
    const float* eW1  = (const float*)d_in[11];
    const float* eb1  = (const float*)d_in[12];
    const float* eW2  = (const float*)d_in[13];
    const float* eb2  = (const float*)d_in[14];
    const float* ln_g = (const float*)d_in[15];
    const float* ln_b = (const float*)d_in[16];
    const float* cW   = (const float*)d_in[17];
    const float* cb   = (const float*)d_in[18];
    float* h = (float*)d_out;

    // ---- workspace layout, total ~226 MB ----
    char* ws = (char*)d_ws;
    int4* es = (int4*)ws;                        ws += (size_t)2 * EE * 16;     // 19.2 MB
    unsigned short* hhi = (unsigned short*)ws;   ws += (size_t)NN * HD * 2;     // 25.6 MB
    unsigned short* hlo = (unsigned short*)ws;   ws += (size_t)NN * HD * 2;     // 25.6 MB
    float* zagg_a = (float*)ws;                  ws += (size_t)NN * HD * 4;     // 51.2 MB
    float* zagg_e = (float*)ws;                  ws += (size_t)NN * HD * 4;     // 51.2 MB
    float* ctx = (float*)ws;                     ws += (size_t)NN * HD * 4;     // 51.2 MB (shared per graph)
    unsigned short* W1thi = (unsigned short*)ws; ws += (size_t)4 * HD * K1 * 2;
    unsigned short* W1tlo = (unsigned short*)ws; ws += (size_t)4 * HD * K1 * 2;
    unsigned short* W2thi = (unsigned short*)ws; ws += (size_t)2 * HD * 256 * 2;
    unsigned short* W2tlo = (unsigned short*)ws; ws += (size_t)2 * HD * 256 * 2;
    unsigned short* cWthi = (unsigned short*)ws; ws += (size_t)2 * HD * HD * 2;
    unsigned short* cWtlo = (unsigned short*)ws; ws += (size_t)2 * HD * HD * 2;
    float* da = (float*)ws;                      ws += (size_t)NN * 4;
    float* de = (float*)ws;                      ws += (size_t)NN * 4;
    // CSR-build scratch aliased into ctx (dead before first k_ctx writes ctx)
    int* cnt = (int*)ctx;
    int* cur = cnt + 2 * NN;
    int* bsum = cur + 2 * NN;
    int* bpre = bsum + 2 * SCB;

    k_input_proj<<<NN / 16, 256, 0, stream>>>(x, W_in, b_in, h, hhi, hlo);

    // CSR build (once per launch; reused by both layers)
    hipMemsetAsync(cnt, 0, (size_t)2 * NN * 4, stream);
    dim3 ge((EE + 255) / 256, 2);
    k_hist<<<ge, 256, 0, stream>>>(a_ei, e_ei, cnt);
    dim3 gs(SCB, 2);
    k_scanA<<<gs, 256, 0, stream>>>(cnt, bsum);
    k_scanB<<<1, 64, 0, stream>>>(bsum, bpre);
    k_scanC<<<gs, 256, 0, stream>>>(cnt, bpre, cur, da, de);
    k_scatter<<<ge, 256, 0, stream>>>(a_ei, a_ea, e_ei, e_ea, cur, es);

    k_prep_all<<<896, 256, 0, stream>>>(aW1, eW1, aW2, eW2, cW,
                                        W1thi, W1tlo, W2thi, W2tlo, cWthi, cWtlo);

    const int W1SZ = (2 * HD + 2) * HD;
    for (int l = 0; l < 2; ++l) {
        hipMemsetAsync(zagg_a, 0, (size_t)2 * NN * HD * 4, stream);  // zagg_a + zagg_e adjacent
        k_ctx<<<1024, 256, 0, stream>>>(hhi, hlo,
            W1thi + (0 + l) * HD * K1, W1tlo + (0 + l) * HD * K1, ab1 + l * HD, ctx);
        k_edge<<<2048, 256, 0, stream>>>(hhi, hlo, es,
            W1thi + (0 + l) * HD * K1, W1tlo + (0 + l) * HD * K1,
            aW1 + (size_t)l * W1SZ, ctx, zagg_a);
        k_ctx<<<1024, 256, 0, stream>>>(hhi, hlo,
            W1thi + (2 + l) * HD * K1, W1tlo + (2 + l) * HD * K1, eb1 + l * HD, ctx);
        k_edge<<<2048, 256, 0, stream>>>(hhi, hlo, es + (size_t)EE,
            W1thi + (2 + l) * HD * K1, W1tlo + (2 + l) * HD * K1,
            eW1 + (size_t)l * W1SZ, ctx, zagg_e);
        k_node<<<512, 256, 0, stream>>>(h, hhi, hlo, zagg_a, zagg_e, da, de,
            W2thi + l * HD * 256, W2tlo + l * HD * 256, ab2 + l * HD, eb2 + l * HD,
            ln_g + l * HD, ln_b + l * HD,
            cWthi + l * HD * HD, cWtlo + l * HD * HD, cb + l * HD);
    }
}

// Round 13
// 1069.947 us; speedup vs baseline: 1.6497x; 1.0712x over previous
//
#include <hip/hip_runtime.h>

#define NN 100000
#define EE 600000
#define FIN 39
#define HD 128
#define K1 256          // W1t layout K (k<128 = target half, k>=128 = source half)
#define NT32 (EE / 32)  // 18750 edge tiles of 32
#define NGRP (NN / 16)  // 6250 node groups of 16
#define LOSCALE 4096.0f
#define INV_LOSCALE (1.0f / 4096.0f)
#define SCB 98          // scan blocks per graph: 98*1024 >= NN

typedef _Float16 f16x8 __attribute__((ext_vector_type(8)));
typedef __attribute__((ext_vector_type(4))) float f32x4;

#define MFMA16(a, b, c) __builtin_amdgcn_mfma_f32_16x16x32_f16((a), (b), (c), 0, 0, 0)

__device__ __forceinline__ void split_hl(float x, unsigned short& hi, unsigned short& lo) {
    union { _Float16 h; unsigned short u; } a, b;
    a.h = (_Float16)x;
    float r = (x - (float)a.h) * LOSCALE;   // scaled residual stays fp16-normal
    b.h = (_Float16)r;
    hi = a.u; lo = b.u;
}

// LDS-only barrier: drains LDS ops (cross-wave staging visibility) but leaves VMEM
// loads in flight. __syncthreads() would emit s_waitcnt vmcnt(0) before s_barrier,
// force-draining the gather prefetch every phase (the R2..R6 hidden serializer).
__device__ __forceinline__ void bar_lds() {
    asm volatile("s_waitcnt lgkmcnt(0)" ::: "memory");
    __builtin_amdgcn_s_barrier();
}

// ---------------- input projection: h = relu(x @ W_in + b_in), fp32; emit hi/lo ----------------
__global__ __launch_bounds__(256) void k_input_proj(
    const float* __restrict__ x, const float* __restrict__ Wi,
    const float* __restrict__ bi, float* __restrict__ h,
    unsigned short* __restrict__ hhi, unsigned short* __restrict__ hlo)
{
    __shared__ float Ws[FIN * HD];
    __shared__ float xs[16][FIN + 1];
    int tid = threadIdx.x;
    for (int i = tid; i < FIN * HD; i += 256) Ws[i] = Wi[i];
    int base = blockIdx.x * 16;
    for (int i = tid; i < 16 * FIN; i += 256) {
        int nd = i / FIN, k = i - nd * FIN;
        xs[nd][k] = x[(size_t)(base + nd) * FIN + k];
    }
    __syncthreads();
    int j = tid & 127, slot = tid >> 7;
    float bj = bi[j];
    for (int r = 0; r < 8; ++r) {
        int nd = slot * 8 + r;
        float acc = bj;
#pragma unroll
        for (int k = 0; k < FIN; ++k) acc += xs[nd][k] * Ws[k * HD + j];
        acc = fmaxf(acc, 0.f);
        int o = (base + nd) * HD + j;
        h[o] = acc;
        unsigned short hv, lv; split_hl(acc, hv, lv);
        hhi[o] = hv; hlo[o] = lv;
    }
}

// ---------------- CSR build ----------------
__global__ __launch_bounds__(256) void k_hist(const int* __restrict__ a_ei, const int* __restrict__ e_ei,
                                              int* __restrict__ cnt) {
    int g = blockIdx.y;
    int gid = blockIdx.x * 256 + threadIdx.x;
    if (gid >= EE) return;
    const int* ei = g ? e_ei : a_ei;
    atomicAdd(&cnt[g * NN + ei[EE + gid]], 1);
}

__global__ __launch_bounds__(256) void k_scanA(const int* __restrict__ cnt, int* __restrict__ bsum) {
    int g = blockIdx.y, b = blockIdx.x, tid = threadIdx.x;
    int base = b * 1024 + tid * 4;
    int s = 0;
#pragma unroll
    for (int j = 0; j < 4; ++j) {
        int i = base + j;
        if (i < NN) s += cnt[g * NN + i];
    }
    __shared__ int lds[256];
    lds[tid] = s; __syncthreads();
    for (int o = 128; o > 0; o >>= 1) {
        if (tid < o) lds[tid] += lds[tid + o];
        __syncthreads();
    }
    if (tid == 0) bsum[g * SCB + b] = lds[0];
}

__global__ __launch_bounds__(64) void k_scanB(const int* __restrict__ bsum, int* __restrict__ bpre) {
    int tid = threadIdx.x;
    if (tid < 2) {
        int run = 0;
        for (int b = 0; b < SCB; ++b) { bpre[tid * SCB + b] = run; run += bsum[tid * SCB + b]; }
    }
}

__global__ __launch_bounds__(256) void k_scanC(const int* __restrict__ cnt, const int* __restrict__ bpre,
                                               int* __restrict__ cur,
                                               float* __restrict__ da, float* __restrict__ de) {
    int g = blockIdx.y, b = blockIdx.x, tid = threadIdx.x;
    float* dg = g ? de : da;
    int base = b * 1024 + tid * 4;
    int c[4]; int ts = 0;
#pragma unroll
    for (int j = 0; j < 4; ++j) {
        int i = base + j;
        c[j] = (i < NN) ? cnt[g * NN + i] : 0;
        ts += c[j];
    }
    __shared__ int lds[256];
    lds[tid] = ts; __syncthreads();
    for (int o = 1; o < 256; o <<= 1) {
        int v = (tid >= o) ? lds[tid - o] : 0;
        __syncthreads();
        lds[tid] += v;
        __syncthreads();
    }
    int run = lds[tid] - ts + bpre[g * SCB + b];
#pragma unroll
    for (int j = 0; j < 4; ++j) {
        int i = base + j;
        if (i < NN) { cur[g * NN + i] = run; dg[i] = (float)c[j]; run += c[j]; }
    }
}

__global__ __launch_bounds__(256) void k_scatter(
    const int* __restrict__ a_ei, const float* __restrict__ a_ea,
    const int* __restrict__ e_ei, const float* __restrict__ e_ea,
    int* __restrict__ cur, int4* __restrict__ es) {
    int g = blockIdx.y;
    int gid = blockIdx.x * 256 + threadIdx.x;
    if (gid >= EE) return;
    const int* ei = g ? e_ei : a_ei;
    const float* ea = g ? e_ea : a_ea;
    int src = ei[gid], tgt = ei[EE + gid];
    int slot = atomicAdd(&cur[g * NN + tgt], 1);
    es[(size_t)g * EE + slot] = make_int4(src, tgt,
        __float_as_int(ea[2 * gid]), __float_as_int(ea[2 * gid + 1]));
}

// ---------------- fused weight prep (hi/lo, n-major transposed) ----------------
__global__ __launch_bounds__(256) void k_prep_all(
    const float* __restrict__ aW1, const float* __restrict__ eW1,
    const float* __restrict__ aW2, const float* __restrict__ eW2,
    const float* __restrict__ cW,
    unsigned short* __restrict__ W1thi, unsigned short* __restrict__ W1tlo,
    unsigned short* __restrict__ W2thi, unsigned short* __restrict__ W2tlo,
    unsigned short* __restrict__ cWthi, unsigned short* __restrict__ cWtlo) {
    int i = blockIdx.x * 256 + threadIdx.x;
    unsigned short hv, lv;
    if (i < 131072) {                       // W1: 4 x [128n][256k]
        int s = i >> 15, r = i & 32767;
        const float* W = ((s < 2) ? aW1 : eW1) + (size_t)(s & 1) * 258 * HD;
        int n = r >> 8, k = r & 255;
        split_hl(W[k * HD + n], hv, lv);
        W1thi[i] = hv; W1tlo[i] = lv;
    } else if (i < 196608) {                // W2: 2 x [128n][256k] ([W2a;W2e])
        int j = i - 131072;
        int l = j >> 15, r = j & 32767;
        int n = r >> 8, k = r & 255;
        float v = (k < HD) ? aW2[(size_t)l * HD * HD + k * HD + n]
                           : eW2[(size_t)l * HD * HD + (k - HD) * HD + n];
        split_hl(v, hv, lv);
        W2thi[j] = hv; W2tlo[j] = lv;
    } else if (i < 229376) {                // cW: 2 x [128n][128k]
        int j = i - 196608;
        int l = j >> 14, r = j & 16383;
        int n = r >> 7, k = r & 127;
        split_hl(cW[(size_t)l * HD * HD + k * HD + n], hv, lv);
        cWthi[j] = hv; cWtlo[j] = lv;
    }
}

// ---------------- target context (persistent; bar_lds so hi/lo prefetch rides barriers) ----------------
// c[t][n] = sum_k<128 h_t[k] W1[k][n] + b1[n]
__global__ __launch_bounds__(256) void k_ctx(
    const unsigned short* __restrict__ hhi, const unsigned short* __restrict__ hlo,
    const unsigned short* __restrict__ Whi, const unsigned short* __restrict__ Wlo,
    const float* __restrict__ b1, float* __restrict__ cc)
{
    __shared__ __align__(16) unsigned short a_hi[16 * 128], a_lo[16 * 128];
    int tid = threadIdx.x;
    int wave = tid >> 6, lane = tid & 63;
    int l16 = lane & 15, quad = lane >> 4;
    int n0 = wave * 32 + l16, n1 = n0 + 16;

    // persistent B fragments (loaded once per block)
    f16x8 bh[2][4], bl[2][4];
#pragma unroll
    for (int b = 0; b < 2; ++b) {
        int n = wave * 32 + b * 16 + l16;
        const unsigned short* ph = Whi + n * K1 + quad * 8;   // target half: k 0..127
        const unsigned short* pl = Wlo + n * K1 + quad * 8;
#pragma unroll
        for (int kt = 0; kt < 4; ++kt) {
            bh[b][kt] = *(const f16x8*)(ph + kt * 32);
            bl[b][kt] = *(const f16x8*)(pl + kt * 32);
        }
    }
    float vb0 = b1[n0], vb1 = b1[n1];

    int nd = tid >> 4, part = tid & 15;
    int pm = part & 7;
    const unsigned short* hsel = (part < 8) ? hhi : hlo;
    unsigned short* msel = ((part < 8) ? a_hi : a_lo) + nd * 128;
    int c0i = (2 * pm) ^ nd, c1i = (2 * pm + 1) ^ nd;

    int stride = gridDim.x;
    int grp = blockIdx.x;

    // prologue prefetch for first group
    uint4 v0, v1;
    {
        const uint4* gpp = (const uint4*)(hsel + (size_t)(grp * 16 + nd) * HD + pm * 16);
        v0 = gpp[0]; v1 = gpp[1];
    }

    for (; grp < NGRP; grp += stride) {
        bar_lds();                          // prev-iter MFMA readers done with a_hi/a_lo
        *(uint4*)(msel + c0i * 8) = v0;
        *(uint4*)(msel + c1i * 8) = v1;
        bar_lds();                          // staged

        // issue next-group prefetch (rides across MFMA + cc stores + loop-top barrier)
        {
            int gnx = grp + stride;
            int pfg = (gnx < NGRP) ? gnx : grp;
            const uint4* gpp = (const uint4*)(hsel + (size_t)(pfg * 16 + nd) * HD + pm * 16);
            v0 = gpp[0]; v1 = gpp[1];
        }

        f32x4 h0 = {0,0,0,0}, h1 = {0,0,0,0}, L0 = {0,0,0,0}, L1 = {0,0,0,0};
#pragma unroll
        for (int kt = 0; kt < 4; ++kt) {
            int ch = ((kt * 4 + quad) ^ l16) * 8;
            f16x8 ah = *(const f16x8*)(a_hi + l16 * 128 + ch);
            f16x8 al = *(const f16x8*)(a_lo + l16 * 128 + ch);
            h0 = MFMA16(ah, bh[0][kt], h0);
            h1 = MFMA16(ah, bh[1][kt], h1);
            L0 = MFMA16(ah, bl[0][kt], L0);
            L0 = MFMA16(al, bh[0][kt], L0);
            L1 = MFMA16(ah, bl[1][kt], L1);
            L1 = MFMA16(al, bh[1][kt], L1);
        }
        int base = grp * 16;
#pragma unroll
        for (int r = 0; r < 4; ++r) {
            int rr = quad * 4 + r;
            float* cp = cc + (size_t)(base + rr) * HD;
            cp[n0] = h0[r] + L0[r] * INV_LOSCALE + vb0;
            cp[n1] = h1[r] + L1[r] * INV_LOSCALE + vb1;
        }
    }
}

// ---------------- edge conv (R13: A-hi-only gather — half the gather bytes, 8 MFMAs/kt) ----------------
// Structure is R9/R12-proven (bar_lds + ctx hoist + tail segsum). Change: the A-operand
// (gathered source rows) drops its lo plane — keep A_hi x B_hi and A_hi x B_lo (weights
// stay full hi/lo precision), drop A_lo x B_hi. Error budget: fp16 A-residual ~4.9e-4 rel,
// x sqrt(128) accum x w_rms 0.06 => ~3e-4/element in z; ~2-3e-3 in h after 2 layers vs
// threshold 0.1106 (measured base 0.0156). Gather: 256B/edge (was 512B); staging LDS
// halves (m_lo gone): ~25.4KB -> 4+ blocks/CU by LDS. 8 parts x 32B per row.
__global__ __launch_bounds__(256, 3) void k_edge(
    const unsigned short* __restrict__ hhi, const unsigned short* __restrict__ hlo,
    const int4* __restrict__ es,          // sorted by target: (src,tgt,ea0,ea1)
    const unsigned short* __restrict__ Whi, const unsigned short* __restrict__ Wlo, // [128][256]
    const float* __restrict__ W1full,     // rows 256/257 for ea
    const float* __restrict__ cctx,       // [node][128]: tgt half + b1
    float* __restrict__ zagg)
{
    __shared__ __align__(16) unsigned short m_hi[32 * 128];
    __shared__ float z_s[32][132];
    __shared__ int   ts_s[32];
    __shared__ float ea_s[2][32];

    int tid = threadIdx.x;
    int wave = tid >> 6, lane = tid & 63;
    int l16 = lane & 15, quad = lane >> 4;
    int n0 = wave * 32 + l16, n1 = n0 + 16;

    // persistent B fragments: source half of W1 (k = 128..255), hi AND lo (full precision)
    f16x8 bhi[2][4], blo[2][4];
#pragma unroll
    for (int b = 0; b < 2; ++b) {
        int n = wave * 32 + b * 16 + l16;
        const unsigned short* ph = Whi + n * K1 + 128 + quad * 8;
        const unsigned short* pl = Wlo + n * K1 + 128 + quad * 8;
#pragma unroll
        for (int kt = 0; kt < 4; ++kt) {
            bhi[b][kt] = *(const f16x8*)(ph + kt * 32);
            blo[b][kt] = *(const f16x8*)(pl + kt * 32);
        }
    }
    float w256_0 = W1full[256 * HD + n0], w257_0 = W1full[257 * HD + n0];
    float w256_1 = W1full[256 * HD + n1], w257_1 = W1full[257 * HD + n1];

    int row = tid >> 3, part = tid & 7;   // 32 rows x 8 parts (32B each, hi plane only)
    unsigned short* msel = m_hi + row * 128;
    int sw = row & 15;
    int c0s = (2 * part) ^ sw, c1s = (2 * part + 1) ^ sw;

    int stride = gridDim.x;
    int tile = blockIdx.x;

    // prologue: q_cur(tile), gather G(tile) from hhi only, q_nxt(tile+stride)
    int4 q_cur = es[tile * 32 + row];
    uint4 G0, G1;
    {
        const uint4* gp = (const uint4*)(hhi + (size_t)q_cur.x * HD + part * 16);
        G0 = gp[0]; G1 = gp[1];
    }
    int tn = tile + stride;
    int4 q_nxt = es[(tn < NT32 ? tn : tile) * 32 + row];

    for (; tile < NT32; tile += stride) {
        bar_lds();                          // A: prev-iter segsum LDS reads done
        if (part == 0) {
            ts_s[row] = q_cur.y;
            ea_s[0][row] = __int_as_float(q_cur.z);
            ea_s[1][row] = __int_as_float(q_cur.w);
        }
        *(uint4*)(msel + c0s * 8) = G0;
        *(uint4*)(msel + c1s * 8) = G1;
        bar_lds();                          // B: staging visible to all waves

        // hoisted ctx loads — oldest VMEM batch of this iteration (ts_s valid post-B)
        float ctx00[4], ctx01[4], ctx10[4], ctx11[4];
#pragma unroll
        for (int r = 0; r < 4; ++r) {
            int r0 = quad * 4 + r, r1 = r0 + 16;
            const float* cp0 = cctx + (size_t)ts_s[r0] * HD;
            const float* cp1 = cctx + (size_t)ts_s[r1] * HD;
            ctx00[r] = cp0[n0]; ctx01[r] = cp0[n1];
            ctx10[r] = cp1[n0]; ctx11[r] = cp1[n1];
        }
        __builtin_amdgcn_sched_barrier(0);  // pin: ctx issued before gather/es below

        // gather for next tile + es two ahead — ride across C/A, waited at next staging
        {
            const uint4* gp = (const uint4*)(hhi + (size_t)q_nxt.x * HD + part * 16);
            G0 = gp[0]; G1 = gp[1];
        }
        int t2 = tile + 2 * stride;
        int4 q_tmp = es[(t2 < NT32 ? t2 : tile) * 32 + row];

        f32x4 aH0 = {0,0,0,0}, aH1 = {0,0,0,0}, aH2 = {0,0,0,0}, aH3 = {0,0,0,0};
        f32x4 aL0 = {0,0,0,0}, aL1 = {0,0,0,0}, aL2 = {0,0,0,0}, aL3 = {0,0,0,0};
#pragma unroll
        for (int kt = 0; kt < 4; ++kt) {
            int ch = ((kt * 4 + quad) ^ l16) * 8;
            f16x8 a0h = *(const f16x8*)(m_hi + l16 * 128 + ch);
            f16x8 a1h = *(const f16x8*)(m_hi + (l16 + 16) * 128 + ch);
            aH0 = MFMA16(a0h, bhi[0][kt], aH0);
            aH1 = MFMA16(a0h, bhi[1][kt], aH1);
            aH2 = MFMA16(a1h, bhi[0][kt], aH2);
            aH3 = MFMA16(a1h, bhi[1][kt], aH3);
            aL0 = MFMA16(a0h, blo[0][kt], aL0);
            aL1 = MFMA16(a0h, blo[1][kt], aL1);
            aL2 = MFMA16(a1h, blo[0][kt], aL2);
            aL3 = MFMA16(a1h, blo[1][kt], aL3);
        }

        // epilogue: + c[tgt] (hoisted regs) + ea rank-2, relu -> z_s
#pragma unroll
        for (int r = 0; r < 4; ++r) {
            int r0 = quad * 4 + r, r1 = r0 + 16;
            float e00 = ea_s[0][r0], e01 = ea_s[1][r0];
            float e10 = ea_s[0][r1], e11 = ea_s[1][r1];
            z_s[r0][n0] = fmaxf(aH0[r] + aL0[r] * INV_LOSCALE + ctx00[r] + e00 * w256_0 + e01 * w257_0, 0.f);
            z_s[r0][n1] = fmaxf(aH1[r] + aL1[r] * INV_LOSCALE + ctx01[r] + e00 * w256_1 + e01 * w257_1, 0.f);
            z_s[r1][n0] = fmaxf(aH2[r] + aL2[r] * INV_LOSCALE + ctx10[r] + e10 * w256_0 + e11 * w257_0, 0.f);
            z_s[r1][n1] = fmaxf(aH3[r] + aL3[r] * INV_LOSCALE + ctx11[r] + e10 * w256_1 + e11 * w257_1, 0.f);
        }
        bar_lds();                          // C: z_s visible

        // segmented sum over 32 sorted rows
        if (tid < 128) {
            int c = tid;
            float run = z_s[0][c];
            int tp = ts_s[0];
            bool open0 = true;
#pragma unroll
            for (int r = 1; r < 32; ++r) {
                int t = ts_s[r];
                float v = z_s[r][c];
                if (t == tp) { run += v; }
                else {
                    float* p = zagg + (size_t)tp * HD + c;
                    if (open0) atomicAdd(p, run);
                    else       *p = run;
                    run = v; tp = t; open0 = false;
                }
            }
            atomicAdd(zagg + (size_t)tp * HD + c, run);
        }

        q_cur = q_nxt; q_nxt = q_tmp;
    }
}

// ---------------- node update (persistent; R9-proven bar_lds + loop-top h/da/de hoist) ----------------
__global__ __launch_bounds__(256) void k_node(
    float* __restrict__ h,
    unsigned short* __restrict__ hhi, unsigned short* __restrict__ hlo,
    const float* __restrict__ za, const float* __restrict__ ze,
    const float* __restrict__ da, const float* __restrict__ de,
    const unsigned short* __restrict__ W2hi, const unsigned short* __restrict__ W2lo,
    const float* __restrict__ b2a, const float* __restrict__ b2e,
    const float* __restrict__ g, const float* __restrict__ bln,
    const unsigned short* __restrict__ cWhi, const unsigned short* __restrict__ cWlo,
    const float* __restrict__ cb)
{
    __shared__ __align__(16) unsigned short a_hi[16][264], a_lo[16][264];
    __shared__ float t1_s[16][132];
    __shared__ __align__(16) unsigned short u_hi[16][136], u_lo[16][136];
    __shared__ float g_s[HD], b_s[HD];
    int tid = threadIdx.x;
    int wave = tid >> 6, lane = tid & 63;
    int l16 = lane & 15, quad = lane >> 4;
    int nb0 = wave * 2;
    int n0 = nb0 * 16 + l16, n1 = n0 + 16;

    if (tid < HD) { g_s[tid] = g[tid]; b_s[tid] = bln[tid]; }

    // persistent weight fragments (W2 + cW in registers, once per block)
    f16x8 b2h[2][8], b2l[2][8], bch[2][4], bcl[2][4];
#pragma unroll
    for (int b = 0; b < 2; ++b) {
        int n = (nb0 + b) * 16 + l16;
        const unsigned short* p2h = W2hi + n * 256 + quad * 8;
        const unsigned short* p2l = W2lo + n * 256 + quad * 8;
#pragma unroll
        for (int kt = 0; kt < 8; ++kt) {
            b2h[b][kt] = *(const f16x8*)(p2h + kt * 32);
            b2l[b][kt] = *(const f16x8*)(p2l + kt * 32);
        }
        const unsigned short* pch = cWhi + n * 128 + quad * 8;
        const unsigned short* pcl = cWlo + n * 128 + quad * 8;
#pragma unroll
        for (int kt = 0; kt < 4; ++kt) {
            bch[b][kt] = *(const f16x8*)(pch + kt * 32);
            bcl[b][kt] = *(const f16x8*)(pcl + kt * 32);
        }
    }
    float vb2a0 = b2a[n0], vb2a1 = b2a[n1];
    float vb2e0 = b2e[n0], vb2e1 = b2e[n1];
    float vcb0 = cb[n0], vcb1 = cb[n1];

    int nd = tid >> 4, part = tid & 15;
    const float* zsel = (part < 8) ? za : ze;
    int pq = part & 7;

    int stride = gridDim.x;
    int grp = blockIdx.x;

    // prologue prefetch of za/ze for first group
    float4 zf0, zf1, zf2, zf3;
    {
        const float4* sp = (const float4*)(zsel + (size_t)(grp * 16 + nd) * HD + pq * 16);
        zf0 = sp[0]; zf1 = sp[1]; zf2 = sp[2]; zf3 = sp[3];
    }

    for (; grp < NGRP; grp += stride) {
        int base = grp * 16;

        // hoisted current-group h/da/de — oldest VMEM batch of this iteration
        float hp[8], dav[4], dev[4];
#pragma unroll
        for (int r = 0; r < 4; ++r) {
            const float* hb = h + (size_t)(base + quad * 4 + r) * HD;
            hp[2 * r]     = hb[n0];
            hp[2 * r + 1] = hb[n1];
            dav[r] = da[base + quad * 4 + r];
            dev[r] = de[base + quad * 4 + r];
        }
        __builtin_amdgcn_sched_barrier(0);  // pin: h/da/de issued before anything below

        bar_lds();                          // S0: prev-iter P1 done reading a_*

        // ---- P0: split prefetched za/ze -> LDS ----
        {
            union { unsigned short s[16]; uint4 q[2]; } Hv, Lv;
            float4 fa[4] = {zf0, zf1, zf2, zf3};
#pragma unroll
            for (int i = 0; i < 4; ++i) {
                split_hl(fa[i].x, Hv.s[4*i+0], Lv.s[4*i+0]);
                split_hl(fa[i].y, Hv.s[4*i+1], Lv.s[4*i+1]);
                split_hl(fa[i].z, Hv.s[4*i+2], Lv.s[4*i+2]);
                split_hl(fa[i].w, Hv.s[4*i+3], Lv.s[4*i+3]);
            }
            int ko = part * 16;
            *(uint4*)&a_hi[nd][ko] = Hv.q[0]; *(uint4*)&a_hi[nd][ko + 8] = Hv.q[1];
            *(uint4*)&a_lo[nd][ko] = Lv.q[0]; *(uint4*)&a_lo[nd][ko + 8] = Lv.q[1];
        }
        bar_lds();                          // S1: staged

        // issue next-group za/ze prefetch (rides across S2/S3/S0)
        {
            int gnx = grp + stride;
            int pfg = (gnx < NGRP) ? gnx : grp;   // clamped; tail values unused
            const float4* sp = (const float4*)(zsel + (size_t)(pfg * 16 + nd) * HD + pq * 16);
            zf0 = sp[0]; zf1 = sp[1]; zf2 = sp[2]; zf3 = sp[3];
        }

        // ---- P1: [za|ze] @ [W2a;W2e] (K=256); h/da/de from hoisted regs ----
        f32x4 acc0 = {0,0,0,0}, acc1 = {0,0,0,0}, accL0 = {0,0,0,0}, accL1 = {0,0,0,0};
#pragma unroll
        for (int kt = 0; kt < 8; ++kt) {
            f16x8 ah = *(const f16x8*)&a_hi[l16][kt * 32 + quad * 8];
            f16x8 al = *(const f16x8*)&a_lo[l16][kt * 32 + quad * 8];
            acc0  = MFMA16(ah, b2h[0][kt], acc0);
            acc1  = MFMA16(ah, b2h[1][kt], acc1);
            accL0 = MFMA16(ah, b2l[0][kt], accL0);
            accL1 = MFMA16(ah, b2l[1][kt], accL1);
            accL0 = MFMA16(al, b2h[0][kt], accL0);
            accL1 = MFMA16(al, b2h[1][kt], accL1);
        }
#pragma unroll
        for (int r = 0; r < 4; ++r) {
            int ndl = quad * 4 + r;
            t1_s[ndl][n0] = acc0[r] + accL0[r] * INV_LOSCALE + hp[2 * r]     + dav[r] * vb2a0 + dev[r] * vb2e0;
            t1_s[ndl][n1] = acc1[r] + accL1[r] * INV_LOSCALE + hp[2 * r + 1] + dav[r] * vb2a1 + dev[r] * vb2e1;
        }
        bar_lds();                          // S2: t1 ready

        // ---- P2: LayerNorm ----
        float v[8]; float s = 0.f, ss = 0.f;
#pragma unroll
        for (int i = 0; i < 8; ++i) { v[i] = t1_s[nd][part * 8 + i]; s += v[i]; ss += v[i] * v[i]; }
#pragma unroll
        for (int m = 1; m < 16; m <<= 1) { s += __shfl_xor(s, m); ss += __shfl_xor(ss, m); }
        float mu = s * (1.f / HD);
        float var = ss * (1.f / HD) - mu * mu;
        float inv = rsqrtf(var + 1e-5f);
        {
            union { unsigned short s[8]; uint4 q; } Hu, Lu;
#pragma unroll
            for (int i = 0; i < 8; ++i) {
                int c = part * 8 + i;
                float u = (v[i] - mu) * inv * g_s[c] + b_s[c];
                t1_s[nd][c] = u;
                split_hl(u, Hu.s[i], Lu.s[i]);
            }
            *(uint4*)&u_hi[nd][part * 8] = Hu.q;
            *(uint4*)&u_lo[nd][part * 8] = Lu.q;
        }
        bar_lds();                          // S3: u ready

        // ---- P3: comb MFMA (persistent bch/bcl) ----
        f32x4 c0 = {0,0,0,0}, c1 = {0,0,0,0}, cL0 = {0,0,0,0}, cL1 = {0,0,0,0};
#pragma unroll
        for (int kt = 0; kt < 4; ++kt) {
            f16x8 ah = *(const f16x8*)&u_hi[l16][kt * 32 + quad * 8];
            f16x8 al = *(const f16x8*)&u_lo[l16][kt * 32 + quad * 8];
            c0  = MFMA16(ah, bch[0][kt], c0);
            c1  = MFMA16(ah, bch[1][kt], c1);
            cL0 = MFMA16(ah, bcl[0][kt], cL0);
            cL1 = MFMA16(ah, bcl[1][kt], cL1);
            cL0 = MFMA16(al, bch[0][kt], cL0);
            cL1 = MFMA16(al, bch[1][kt], cL1);
        }
#pragma unroll
        for (int r = 0; r < 4; ++r) {
            int ndl = quad * 4 + r;
            int go = (base + ndl) * HD;
            float u0 = t1_s[ndl][n0], u1 = t1_s[ndl][n1];
            float r0 = fmaxf(c0[r] + cL0[r] * INV_LOSCALE + vcb0, 0.f);
            float r1 = fmaxf(c1[r] + cL1[r] * INV_LOSCALE + vcb1, 0.f);
            float o0 = u0 + r0, o1 = u1 + r1;
            h[go + n0] = o0; h[go + n1] = o1;
            unsigned short hv, lv;
            split_hl(o0, hv, lv); hhi[go + n0] = hv; hlo[go + n0] = lv;
            split_hl(o1, hv, lv); hhi[go + n1] = hv; hlo[go + n1] = lv;
        }
    }
}

extern "C" void kernel_launch(void* const* d_in, const int* in_sizes, int n_in,
                              void* d_out, int out_size, void* d_ws, size_t ws_size,
                              hipStream_t stream) {
    const float* x    = (const float*)d_in[0];
    const int*   a_ei = (const int*)d_in[1];
    const float* a_ea = (const float*)d_in[2];
    const int*   e_ei = (const int*)d_in[3];
    const float* e_ea = (const float*)d_in[4];
    const float* W_in = (const float*)d_in[5];
    const float* b_in = (const float*)d_in[6];
    const float* aW1  = (const float*)d_in[7];
    const float* ab1  = (const float*)d_in[8];
    const float* aW2  = (const float*)d_in[9];
    const float* ab2  = (const float*)d_in[10];
    const float* eW1  = (const float*)d_in[11];
    const float* eb1  = (const float*)d_in[12];
    const float* eW2  = (const float*)d_in[13];
    const float* eb2  = (const float*)d_in[14];
    const float* ln_g = (const float*)d_in[15];
    const float* ln_b = (const float*)d_in[16];
    const float* cW   = (const float*)d_in[17];
    const float* cb   = (const float*)d_in[18];
    float* h = (float*)d_out;

    // ---- workspace layout, total ~226 MB ----
    char* ws = (char*)d_ws;
    int4* es = (int4*)ws;                        ws += (size_t)2 * EE * 16;     // 19.2 MB
    unsigned short* hhi = (unsigned short*)ws;   ws += (size_t)NN * HD * 2;     // 25.6 MB
    unsigned short* hlo = (unsigned short*)ws;   ws += (size_t)NN * HD * 2;     // 25.6 MB
    float* zagg_a = (float*)ws;                  ws += (size_t)NN * HD * 4;     // 51.2 MB
    float* zagg_e = (float*)ws;                  ws += (size_t)NN * HD * 4;     // 51.2 MB
    float* ctx = (float*)ws;                     ws += (size_t)NN * HD * 4;     // 51.2 MB (shared per graph)
    unsigned short* W1thi = (unsigned short*)ws; ws += (size_t)4 * HD * K1 * 2;
    unsigned short* W1tlo = (unsigned short*)ws; ws += (size_t)4 * HD * K1 * 2;
    unsigned short* W2thi = (unsigned short*)ws; ws += (size_t)2 * HD * 256 * 2;
    unsigned short* W2tlo = (unsigned short*)ws; ws += (size_t)2 * HD * 256 * 2;
    unsigned short* cWthi = (unsigned short*)ws; ws += (size_t)2 * HD * HD * 2;
    unsigned short* cWtlo = (unsigned short*)ws; ws += (size_t)2 * HD * HD * 2;
    float* da = (float*)ws;                      ws += (size_t)NN * 4;
    float* de = (float*)ws;                      ws += (size_t)NN * 4;
    // CSR-build scratch aliased into ctx (dead before first k_ctx writes ctx)
    int* cnt = (int*)ctx;
    int* cur = cnt + 2 * NN;
    int* bsum = cur + 2 * NN;
    int* bpre = bsum + 2 * SCB;

    k_input_proj<<<NN / 16, 256, 0, stream>>>(x, W_in, b_in, h, hhi, hlo);

    // CSR build (once per launch; reused by both layers)
    hipMemsetAsync(cnt, 0, (size_t)2 * NN * 4, stream);
    dim3 ge((EE + 255) / 256, 2);
    k_hist<<<ge, 256, 0, stream>>>(a_ei, e_ei, cnt);
    dim3 gs(SCB, 2);
    k_scanA<<<gs, 256, 0, stream>>>(cnt, bsum);
    k_scanB<<<1, 64, 0, stream>>>(bsum, bpre);
    k_scanC<<<gs, 256, 0, stream>>>(cnt, bpre, cur, da, de);
    k_scatter<<<ge, 256, 0, stream>>>(a_ei, a_ea, e_ei, e_ea, cur, es);

    k_prep_all<<<896, 256, 0, stream>>>(aW1, eW1, aW2, eW2, cW,
                                        W1thi, W1tlo, W2thi, W2tlo, cWthi, cWtlo);

    const int W1SZ = (2 * HD + 2) * HD;
    for (int l = 0; l < 2; ++l) {
        hipMemsetAsync(zagg_a, 0, (size_t)2 * NN * HD * 4, stream);  // zagg_a + zagg_e adjacent
        k_ctx<<<1024, 256, 0, stream>>>(hhi, hlo,
            W1thi + (0 + l) * HD * K1, W1tlo + (0 + l) * HD * K1, ab1 + l * HD, ctx);
        k_edge<<<2048, 256, 0, stream>>>(hhi, hlo, es,
            W1thi + (0 + l) * HD * K1, W1tlo + (0 + l) * HD * K1,
            aW1 + (size_t)l * W1SZ, ctx, zagg_a);
        k_ctx<<<1024, 256, 0, stream>>>(hhi, hlo,
            W1thi + (2 + l) * HD * K1, W1tlo + (2 + l) * HD * K1, eb1 + l * HD, ctx);
        k_edge<<<2048, 256, 0, stream>>>(hhi, hlo, es + (size_t)EE,
            W1thi + (2 + l) * HD * K1, W1tlo + (2 + l) * HD * K1,
            eW1 + (size_t)l * W1SZ, ctx, zagg_e);
        k_node<<<512, 256, 0, stream>>>(h, hhi, hlo, zagg_a, zagg_e, da, de,
            W2thi + l * HD * 256, W2tlo + l * HD * 256, ab2 + l * HD, eb2 + l * HD,
            ln_g + l * HD, ln_b + l * HD,
            cWthi + l * HD * HD, cWtlo + l * HD * HD, cb + l * HD);
    }
}

// Round 14
// 933.837 us; speedup vs baseline: 1.8902x; 1.1458x over previous
//
#include <hip/hip_runtime.h>

#define NN 100000
#define EE 600000
#define FIN 39
#define HD 128
#define K1 256          // W1t layout K (k<128 = target half, k>=128 = source half)
#define NT32 (EE / 32)  // 18750 edge tiles of 32
#define NGRP (NN / 16)  // 6250 node groups of 16
#define LOSCALE 4096.0f
#define INV_LOSCALE (1.0f / 4096.0f)
#define SCB 98          // scan blocks per graph: 98*1024 >= NN

typedef _Float16 f16x8 __attribute__((ext_vector_type(8)));
typedef __attribute__((ext_vector_type(4))) float f32x4;

#define MFMA16(a, b, c) __builtin_amdgcn_mfma_f32_16x16x32_f16((a), (b), (c), 0, 0, 0)

__device__ __forceinline__ void split_hl(float x, unsigned short& hi, unsigned short& lo) {
    union { _Float16 h; unsigned short u; } a, b;
    a.h = (_Float16)x;
    float r = (x - (float)a.h) * LOSCALE;   // scaled residual stays fp16-normal
    b.h = (_Float16)r;
    hi = a.u; lo = b.u;
}

// LDS-only barrier: drains LDS ops (cross-wave staging visibility) but leaves VMEM
// loads in flight. __syncthreads() would emit s_waitcnt vmcnt(0) before s_barrier,
// force-draining the gather prefetch every phase (the R2..R6 hidden serializer).
__device__ __forceinline__ void bar_lds() {
    asm volatile("s_waitcnt lgkmcnt(0)" ::: "memory");
    __builtin_amdgcn_s_barrier();
}

// ---------------- input projection: h = relu(x @ W_in + b_in), fp32; emit hi/lo ----------------
__global__ __launch_bounds__(256) void k_input_proj(
    const float* __restrict__ x, const float* __restrict__ Wi,
    const float* __restrict__ bi, float* __restrict__ h,
    unsigned short* __restrict__ hhi, unsigned short* __restrict__ hlo)
{
    __shared__ float Ws[FIN * HD];
    __shared__ float xs[16][FIN + 1];
    int tid = threadIdx.x;
    for (int i = tid; i < FIN * HD; i += 256) Ws[i] = Wi[i];
    int base = blockIdx.x * 16;
    for (int i = tid; i < 16 * FIN; i += 256) {
        int nd = i / FIN, k = i - nd * FIN;
        xs[nd][k] = x[(size_t)(base + nd) * FIN + k];
    }
    __syncthreads();
    int j = tid & 127, slot = tid >> 7;
    float bj = bi[j];
    for (int r = 0; r < 8; ++r) {
        int nd = slot * 8 + r;
        float acc = bj;
#pragma unroll
        for (int k = 0; k < FIN; ++k) acc += xs[nd][k] * Ws[k * HD + j];
        acc = fmaxf(acc, 0.f);
        int o = (base + nd) * HD + j;
        h[o] = acc;
        unsigned short hv, lv; split_hl(acc, hv, lv);
        hhi[o] = hv; hlo[o] = lv;
    }
}

// ---------------- CSR build ----------------
__global__ __launch_bounds__(256) void k_hist(const int* __restrict__ a_ei, const int* __restrict__ e_ei,
                                              int* __restrict__ cnt) {
    int g = blockIdx.y;
    int gid = blockIdx.x * 256 + threadIdx.x;
    if (gid >= EE) return;
    const int* ei = g ? e_ei : a_ei;
    atomicAdd(&cnt[g * NN + ei[EE + gid]], 1);
}

__global__ __launch_bounds__(256) void k_scanA(const int* __restrict__ cnt, int* __restrict__ bsum) {
    int g = blockIdx.y, b = blockIdx.x, tid = threadIdx.x;
    int base = b * 1024 + tid * 4;
    int s = 0;
#pragma unroll
    for (int j = 0; j < 4; ++j) {
        int i = base + j;
        if (i < NN) s += cnt[g * NN + i];
    }
    __shared__ int lds[256];
    lds[tid] = s; __syncthreads();
    for (int o = 128; o > 0; o >>= 1) {
        if (tid < o) lds[tid] += lds[tid + o];
        __syncthreads();
    }
    if (tid == 0) bsum[g * SCB + b] = lds[0];
}

__global__ __launch_bounds__(64) void k_scanB(const int* __restrict__ bsum, int* __restrict__ bpre) {
    int tid = threadIdx.x;
    if (tid < 2) {
        int run = 0;
        for (int b = 0; b < SCB; ++b) { bpre[tid * SCB + b] = run; run += bsum[tid * SCB + b]; }
    }
}

__global__ __launch_bounds__(256) void k_scanC(const int* __restrict__ cnt, const int* __restrict__ bpre,
                                               int* __restrict__ cur,
                                               float* __restrict__ da, float* __restrict__ de) {
    int g = blockIdx.y, b = blockIdx.x, tid = threadIdx.x;
    float* dg = g ? de : da;
    int base = b * 1024 + tid * 4;
    int c[4]; int ts = 0;
#pragma unroll
    for (int j = 0; j < 4; ++j) {
        int i = base + j;
        c[j] = (i < NN) ? cnt[g * NN + i] : 0;
        ts += c[j];
    }
    __shared__ int lds[256];
    lds[tid] = ts; __syncthreads();
    for (int o = 1; o < 256; o <<= 1) {
        int v = (tid >= o) ? lds[tid - o] : 0;
        __syncthreads();
        lds[tid] += v;
        __syncthreads();
    }
    int run = lds[tid] - ts + bpre[g * SCB + b];
#pragma unroll
    for (int j = 0; j < 4; ++j) {
        int i = base + j;
        if (i < NN) { cur[g * NN + i] = run; dg[i] = (float)c[j]; run += c[j]; }
    }
}

__global__ __launch_bounds__(256) void k_scatter(
    const int* __restrict__ a_ei, const float* __restrict__ a_ea,
    const int* __restrict__ e_ei, const float* __restrict__ e_ea,
    int* __restrict__ cur, int4* __restrict__ es) {
    int g = blockIdx.y;
    int gid = blockIdx.x * 256 + threadIdx.x;
    if (gid >= EE) return;
    const int* ei = g ? e_ei : a_ei;
    const float* ea = g ? e_ea : a_ea;
    int src = ei[gid], tgt = ei[EE + gid];
    int slot = atomicAdd(&cur[g * NN + tgt], 1);
    es[(size_t)g * EE + slot] = make_int4(src, tgt,
        __float_as_int(ea[2 * gid]), __float_as_int(ea[2 * gid + 1]));
}

// ---------------- fused weight prep (hi/lo, n-major transposed) ----------------
__global__ __launch_bounds__(256) void k_prep_all(
    const float* __restrict__ aW1, const float* __restrict__ eW1,
    const float* __restrict__ aW2, const float* __restrict__ eW2,
    const float* __restrict__ cW,
    unsigned short* __restrict__ W1thi, unsigned short* __restrict__ W1tlo,
    unsigned short* __restrict__ W2thi, unsigned short* __restrict__ W2tlo,
    unsigned short* __restrict__ cWthi, unsigned short* __restrict__ cWtlo) {
    int i = blockIdx.x * 256 + threadIdx.x;
    unsigned short hv, lv;
    if (i < 131072) {                       // W1: 4 x [128n][256k]
        int s = i >> 15, r = i & 32767;
        const float* W = ((s < 2) ? aW1 : eW1) + (size_t)(s & 1) * 258 * HD;
        int n = r >> 8, k = r & 255;
        split_hl(W[k * HD + n], hv, lv);
        W1thi[i] = hv; W1tlo[i] = lv;
    } else if (i < 196608) {                // W2: 2 x [128n][256k] ([W2a;W2e])
        int j = i - 131072;
        int l = j >> 15, r = j & 32767;
        int n = r >> 8, k = r & 255;
        float v = (k < HD) ? aW2[(size_t)l * HD * HD + k * HD + n]
                           : eW2[(size_t)l * HD * HD + (k - HD) * HD + n];
        split_hl(v, hv, lv);
        W2thi[j] = hv; W2tlo[j] = lv;
    } else if (i < 229376) {                // cW: 2 x [128n][128k]
        int j = i - 196608;
        int l = j >> 14, r = j & 16383;
        int n = r >> 7, k = r & 127;
        split_hl(cW[(size_t)l * HD * HD + k * HD + n], hv, lv);
        cWthi[j] = hv; cWtlo[j] = lv;
    }
}

// ---------------- target context (persistent; bar_lds so hi/lo prefetch rides barriers) ----------------
// c[t][n] = sum_k<128 h_t[k] W1[k][n] + b1[n]  (full hi/lo precision — carries b1 + tgt half)
__global__ __launch_bounds__(256) void k_ctx(
    const unsigned short* __restrict__ hhi, const unsigned short* __restrict__ hlo,
    const unsigned short* __restrict__ Whi, const unsigned short* __restrict__ Wlo,
    const float* __restrict__ b1, float* __restrict__ cc)
{
    __shared__ __align__(16) unsigned short a_hi[16 * 128], a_lo[16 * 128];
    int tid = threadIdx.x;
    int wave = tid >> 6, lane = tid & 63;
    int l16 = lane & 15, quad = lane >> 4;
    int n0 = wave * 32 + l16, n1 = n0 + 16;

    // persistent B fragments (loaded once per block)
    f16x8 bh[2][4], bl[2][4];
#pragma unroll
    for (int b = 0; b < 2; ++b) {
        int n = wave * 32 + b * 16 + l16;
        const unsigned short* ph = Whi + n * K1 + quad * 8;   // target half: k 0..127
        const unsigned short* pl = Wlo + n * K1 + quad * 8;
#pragma unroll
        for (int kt = 0; kt < 4; ++kt) {
            bh[b][kt] = *(const f16x8*)(ph + kt * 32);
            bl[b][kt] = *(const f16x8*)(pl + kt * 32);
        }
    }
    float vb0 = b1[n0], vb1 = b1[n1];

    int nd = tid >> 4, part = tid & 15;
    int pm = part & 7;
    const unsigned short* hsel = (part < 8) ? hhi : hlo;
    unsigned short* msel = ((part < 8) ? a_hi : a_lo) + nd * 128;
    int c0i = (2 * pm) ^ nd, c1i = (2 * pm + 1) ^ nd;

    int stride = gridDim.x;
    int grp = blockIdx.x;

    // prologue prefetch for first group
    uint4 v0, v1;
    {
        const uint4* gpp = (const uint4*)(hsel + (size_t)(grp * 16 + nd) * HD + pm * 16);
        v0 = gpp[0]; v1 = gpp[1];
    }

    for (; grp < NGRP; grp += stride) {
        bar_lds();                          // prev-iter MFMA readers done with a_hi/a_lo
        *(uint4*)(msel + c0i * 8) = v0;
        *(uint4*)(msel + c1i * 8) = v1;
        bar_lds();                          // staged

        // issue next-group prefetch (rides across MFMA + cc stores + loop-top barrier)
        {
            int gnx = grp + stride;
            int pfg = (gnx < NGRP) ? gnx : grp;
            const uint4* gpp = (const uint4*)(hsel + (size_t)(pfg * 16 + nd) * HD + pm * 16);
            v0 = gpp[0]; v1 = gpp[1];
        }

        f32x4 h0 = {0,0,0,0}, h1 = {0,0,0,0}, L0 = {0,0,0,0}, L1 = {0,0,0,0};
#pragma unroll
        for (int kt = 0; kt < 4; ++kt) {
            int ch = ((kt * 4 + quad) ^ l16) * 8;
            f16x8 ah = *(const f16x8*)(a_hi + l16 * 128 + ch);
            f16x8 al = *(const f16x8*)(a_lo + l16 * 128 + ch);
            h0 = MFMA16(ah, bh[0][kt], h0);
            h1 = MFMA16(ah, bh[1][kt], h1);
            L0 = MFMA16(ah, bl[0][kt], L0);
            L0 = MFMA16(al, bh[0][kt], L0);
            L1 = MFMA16(ah, bl[1][kt], L1);
            L1 = MFMA16(al, bh[1][kt], L1);
        }
        int base = grp * 16;
#pragma unroll
        for (int r = 0; r < 4; ++r) {
            int rr = quad * 4 + r;
            float* cp = cc + (size_t)(base + rr) * HD;
            cp[n0] = h0[r] + L0[r] * INV_LOSCALE + vb0;
            cp[n1] = h1[r] + L1[r] * INV_LOSCALE + vb1;
        }
    }
}

// ---------------- edge conv (R14: pure-fp16 A and B — 4 MFMAs/kt, minimal registers) ----------------
// R13 dropped A_lo; R14 drops B_lo too: z_src = m_hi . W1src_hi (ctx keeps full precision,
// b1 + target half accumulated in fp32; ea terms fp32). Error: W-residual ~4.9e-4 rel, same
// magnitude as R13's A-drop which moved absmax 0.0156->0.0312; expect ~0.045-0.06 vs
// threshold 0.1106. Wins: -32 fragment VGPRs, -16 acc VGPRs (unified-file occupancy limit
// rises ~2.3 -> ~4 blocks/CU), MFMAs 8->4 per kt. Structure unchanged (bar_lds + ctx hoist).
__global__ __launch_bounds__(256, 3) void k_edge(
    const unsigned short* __restrict__ hhi, const unsigned short* __restrict__ hlo,
    const int4* __restrict__ es,          // sorted by target: (src,tgt,ea0,ea1)
    const unsigned short* __restrict__ Whi, const unsigned short* __restrict__ Wlo, // [128][256]
    const float* __restrict__ W1full,     // rows 256/257 for ea
    const float* __restrict__ cctx,       // [node][128]: tgt half + b1
    float* __restrict__ zagg)
{
    __shared__ __align__(16) unsigned short m_hi[32 * 128];
    __shared__ float z_s[32][132];
    __shared__ int   ts_s[32];
    __shared__ float ea_s[2][32];

    int tid = threadIdx.x;
    int wave = tid >> 6, lane = tid & 63;
    int l16 = lane & 15, quad = lane >> 4;
    int n0 = wave * 32 + l16, n1 = n0 + 16;

    // persistent B fragments: source half of W1 (k = 128..255), hi plane only
    f16x8 bhi[2][4];
#pragma unroll
    for (int b = 0; b < 2; ++b) {
        int n = wave * 32 + b * 16 + l16;
        const unsigned short* ph = Whi + n * K1 + 128 + quad * 8;
#pragma unroll
        for (int kt = 0; kt < 4; ++kt) {
            bhi[b][kt] = *(const f16x8*)(ph + kt * 32);
        }
    }
    float w256_0 = W1full[256 * HD + n0], w257_0 = W1full[257 * HD + n0];
    float w256_1 = W1full[256 * HD + n1], w257_1 = W1full[257 * HD + n1];

    int row = tid >> 3, part = tid & 7;   // 32 rows x 8 parts (32B each, hi plane only)
    unsigned short* msel = m_hi + row * 128;
    int sw = row & 15;
    int c0s = (2 * part) ^ sw, c1s = (2 * part + 1) ^ sw;

    int stride = gridDim.x;
    int tile = blockIdx.x;

    // prologue: q_cur(tile), gather G(tile) from hhi only, q_nxt(tile+stride)
    int4 q_cur = es[tile * 32 + row];
    uint4 G0, G1;
    {
        const uint4* gp = (const uint4*)(hhi + (size_t)q_cur.x * HD + part * 16);
        G0 = gp[0]; G1 = gp[1];
    }
    int tn = tile + stride;
    int4 q_nxt = es[(tn < NT32 ? tn : tile) * 32 + row];

    for (; tile < NT32; tile += stride) {
        bar_lds();                          // A: prev-iter segsum LDS reads done
        if (part == 0) {
            ts_s[row] = q_cur.y;
            ea_s[0][row] = __int_as_float(q_cur.z);
            ea_s[1][row] = __int_as_float(q_cur.w);
        }
        *(uint4*)(msel + c0s * 8) = G0;
        *(uint4*)(msel + c1s * 8) = G1;
        bar_lds();                          // B: staging visible to all waves

        // hoisted ctx loads — oldest VMEM batch of this iteration (ts_s valid post-B)
        float ctx00[4], ctx01[4], ctx10[4], ctx11[4];
#pragma unroll
        for (int r = 0; r < 4; ++r) {
            int r0 = quad * 4 + r, r1 = r0 + 16;
            const float* cp0 = cctx + (size_t)ts_s[r0] * HD;
            const float* cp1 = cctx + (size_t)ts_s[r1] * HD;
            ctx00[r] = cp0[n0]; ctx01[r] = cp0[n1];
            ctx10[r] = cp1[n0]; ctx11[r] = cp1[n1];
        }
        __builtin_amdgcn_sched_barrier(0);  // pin: ctx issued before gather/es below

        // gather for next tile + es two ahead — ride across C/A, waited at next staging
        {
            const uint4* gp = (const uint4*)(hhi + (size_t)q_nxt.x * HD + part * 16);
            G0 = gp[0]; G1 = gp[1];
        }
        int t2 = tile + 2 * stride;
        int4 q_tmp = es[(t2 < NT32 ? t2 : tile) * 32 + row];

        f32x4 aH0 = {0,0,0,0}, aH1 = {0,0,0,0}, aH2 = {0,0,0,0}, aH3 = {0,0,0,0};
#pragma unroll
        for (int kt = 0; kt < 4; ++kt) {
            int ch = ((kt * 4 + quad) ^ l16) * 8;
            f16x8 a0h = *(const f16x8*)(m_hi + l16 * 128 + ch);
            f16x8 a1h = *(const f16x8*)(m_hi + (l16 + 16) * 128 + ch);
            aH0 = MFMA16(a0h, bhi[0][kt], aH0);
            aH1 = MFMA16(a0h, bhi[1][kt], aH1);
            aH2 = MFMA16(a1h, bhi[0][kt], aH2);
            aH3 = MFMA16(a1h, bhi[1][kt], aH3);
        }

        // epilogue: + c[tgt] (hoisted regs) + ea rank-2, relu -> z_s
#pragma unroll
        for (int r = 0; r < 4; ++r) {
            int r0 = quad * 4 + r, r1 = r0 + 16;
            float e00 = ea_s[0][r0], e01 = ea_s[1][r0];
            float e10 = ea_s[0][r1], e11 = ea_s[1][r1];
            z_s[r0][n0] = fmaxf(aH0[r] + ctx00[r] + e00 * w256_0 + e01 * w257_0, 0.f);
            z_s[r0][n1] = fmaxf(aH1[r] + ctx01[r] + e00 * w256_1 + e01 * w257_1, 0.f);
            z_s[r1][n0] = fmaxf(aH2[r] + ctx10[r] + e10 * w256_0 + e11 * w257_0, 0.f);
            z_s[r1][n1] = fmaxf(aH3[r] + ctx11[r] + e10 * w256_1 + e11 * w257_1, 0.f);
        }
        bar_lds();                          // C: z_s visible

        // segmented sum over 32 sorted rows
        if (tid < 128) {
            int c = tid;
            float run = z_s[0][c];
            int tp = ts_s[0];
            bool open0 = true;
#pragma unroll
            for (int r = 1; r < 32; ++r) {
                int t = ts_s[r];
                float v = z_s[r][c];
                if (t == tp) { run += v; }
                else {
                    float* p = zagg + (size_t)tp * HD + c;
                    if (open0) atomicAdd(p, run);
                    else       *p = run;
                    run = v; tp = t; open0 = false;
                }
            }
            atomicAdd(zagg + (size_t)tp * HD + c, run);
        }

        q_cur = q_nxt; q_nxt = q_tmp;
    }
}

// ---------------- node update (persistent; R9-proven bar_lds + loop-top h/da/de hoist) ----------------
__global__ __launch_bounds__(256) void k_node(
    float* __restrict__ h,
    unsigned short* __restrict__ hhi, unsigned short* __restrict__ hlo,
    const float* __restrict__ za, const float* __restrict__ ze,
    const float* __restrict__ da, const float* __restrict__ de,
    const unsigned short* __restrict__ W2hi, const unsigned short* __restrict__ W2lo,
    const float* __restrict__ b2a, const float* __restrict__ b2e,
    const float* __restrict__ g, const float* __restrict__ bln,
    const unsigned short* __restrict__ cWhi, const unsigned short* __restrict__ cWlo,
    const float* __restrict__ cb)
{
    __shared__ __align__(16) unsigned short a_hi[16][264], a_lo[16][264];
    __shared__ float t1_s[16][132];
    __shared__ __align__(16) unsigned short u_hi[16][136], u_lo[16][136];
    __shared__ float g_s[HD], b_s[HD];
    int tid = threadIdx.x;
    int wave = tid >> 6, lane = tid & 63;
    int l16 = lane & 15, quad = lane >> 4;
    int nb0 = wave * 2;
    int n0 = nb0 * 16 + l16, n1 = n0 + 16;

    if (tid < HD) { g_s[tid] = g[tid]; b_s[tid] = bln[tid]; }

    // persistent weight fragments (W2 + cW in registers, once per block)
    f16x8 b2h[2][8], b2l[2][8], bch[2][4], bcl[2][4];
#pragma unroll
    for (int b = 0; b < 2; ++b) {
        int n = (nb0 + b) * 16 + l16;
        const unsigned short* p2h = W2hi + n * 256 + quad * 8;
        const unsigned short* p2l = W2lo + n * 256 + quad * 8;
#pragma unroll
        for (int kt = 0; kt < 8; ++kt) {
            b2h[b][kt] = *(const f16x8*)(p2h + kt * 32);
            b2l[b][kt] = *(const f16x8*)(p2l + kt * 32);
        }
        const unsigned short* pch = cWhi + n * 128 + quad * 8;
        const unsigned short* pcl = cWlo + n * 128 + quad * 8;
#pragma unroll
        for (int kt = 0; kt < 4; ++kt) {
            bch[b][kt] = *(const f16x8*)(pch + kt * 32);
            bcl[b][kt] = *(const f16x8*)(pcl + kt * 32);
        }
    }
    float vb2a0 = b2a[n0], vb2a1 = b2a[n1];
    float vb2e0 = b2e[n0], vb2e1 = b2e[n1];
    float vcb0 = cb[n0], vcb1 = cb[n1];

    int nd = tid >> 4, part = tid & 15;
    const float* zsel = (part < 8) ? za : ze;
    int pq = part & 7;

    int stride = gridDim.x;
    int grp = blockIdx.x;

    // prologue prefetch of za/ze for first group
    float4 zf0, zf1, zf2, zf3;
    {
        const float4* sp = (const float4*)(zsel + (size_t)(grp * 16 + nd) * HD + pq * 16);
        zf0 = sp[0]; zf1 = sp[1]; zf2 = sp[2]; zf3 = sp[3];
    }

    for (; grp < NGRP; grp += stride) {
        int base = grp * 16;

        // hoisted current-group h/da/de — oldest VMEM batch of this iteration
        float hp[8], dav[4], dev[4];
#pragma unroll
        for (int r = 0; r < 4; ++r) {
            const float* hb = h + (size_t)(base + quad * 4 + r) * HD;
            hp[2 * r]     = hb[n0];
            hp[2 * r + 1] = hb[n1];
            dav[r] = da[base + quad * 4 + r];
            dev[r] = de[base + quad * 4 + r];
        }
        __builtin_amdgcn_sched_barrier(0);  // pin: h/da/de issued before anything below

        bar_lds();                          // S0: prev-iter P1 done reading a_*

        // ---- P0: split prefetched za/ze -> LDS ----
        {
            union { unsigned short s[16]; uint4 q[2]; } Hv, Lv;
            float4 fa[4] = {zf0, zf1, zf2, zf3};
#pragma unroll
            for (int i = 0; i < 4; ++i) {
                split_hl(fa[i].x, Hv.s[4*i+0], Lv.s[4*i+0]);
                split_hl(fa[i].y, Hv.s[4*i+1], Lv.s[4*i+1]);
                split_hl(fa[i].z, Hv.s[4*i+2], Lv.s[4*i+2]);
                split_hl(fa[i].w, Hv.s[4*i+3], Lv.s[4*i+3]);
            }
            int ko = part * 16;
            *(uint4*)&a_hi[nd][ko] = Hv.q[0]; *(uint4*)&a_hi[nd][ko + 8] = Hv.q[1];
            *(uint4*)&a_lo[nd][ko] = Lv.q[0]; *(uint4*)&a_lo[nd][ko + 8] = Lv.q[1];
        }
        bar_lds();                          // S1: staged

        // issue next-group za/ze prefetch (rides across S2/S3/S0)
        {
            int gnx = grp + stride;
            int pfg = (gnx < NGRP) ? gnx : grp;   // clamped; tail values unused
            const float4* sp = (const float4*)(zsel + (size_t)(pfg * 16 + nd) * HD + pq * 16);
            zf0 = sp[0]; zf1 = sp[1]; zf2 = sp[2]; zf3 = sp[3];
        }

        // ---- P1: [za|ze] @ [W2a;W2e] (K=256); h/da/de from hoisted regs ----
        f32x4 acc0 = {0,0,0,0}, acc1 = {0,0,0,0}, accL0 = {0,0,0,0}, accL1 = {0,0,0,0};
#pragma unroll
        for (int kt = 0; kt < 8; ++kt) {
            f16x8 ah = *(const f16x8*)&a_hi[l16][kt * 32 + quad * 8];
            f16x8 al = *(const f16x8*)&a_lo[l16][kt * 32 + quad * 8];
            acc0  = MFMA16(ah, b2h[0][kt], acc0);
            acc1  = MFMA16(ah, b2h[1][kt], acc1);
            accL0 = MFMA16(ah, b2l[0][kt], accL0);
            accL1 = MFMA16(ah, b2l[1][kt], accL1);
            accL0 = MFMA16(al, b2h[0][kt], accL0);
            accL1 = MFMA16(al, b2h[1][kt], accL1);
        }
#pragma unroll
        for (int r = 0; r < 4; ++r) {
            int ndl = quad * 4 + r;
            t1_s[ndl][n0] = acc0[r] + accL0[r] * INV_LOSCALE + hp[2 * r]     + dav[r] * vb2a0 + dev[r] * vb2e0;
            t1_s[ndl][n1] = acc1[r] + accL1[r] * INV_LOSCALE + hp[2 * r + 1] + dav[r] * vb2a1 + dev[r] * vb2e1;
        }
        bar_lds();                          // S2: t1 ready

        // ---- P2: LayerNorm ----
        float v[8]; float s = 0.f, ss = 0.f;
#pragma unroll
        for (int i = 0; i < 8; ++i) { v[i] = t1_s[nd][part * 8 + i]; s += v[i]; ss += v[i] * v[i]; }
#pragma unroll
        for (int m = 1; m < 16; m <<= 1) { s += __shfl_xor(s, m); ss += __shfl_xor(ss, m); }
        float mu = s * (1.f / HD);
        float var = ss * (1.f / HD) - mu * mu;
        float inv = rsqrtf(var + 1e-5f);
        {
            union { unsigned short s[8]; uint4 q; } Hu, Lu;
#pragma unroll
            for (int i = 0; i < 8; ++i) {
                int c = part * 8 + i;
                float u = (v[i] - mu) * inv * g_s[c] + b_s[c];
                t1_s[nd][c] = u;
                split_hl(u, Hu.s[i], Lu.s[i]);
            }
            *(uint4*)&u_hi[nd][part * 8] = Hu.q;
            *(uint4*)&u_lo[nd][part * 8] = Lu.q;
        }
        bar_lds();                          // S3: u ready

        // ---- P3: comb MFMA (persistent bch/bcl) ----
        f32x4 c0 = {0,0,0,0}, c1 = {0,0,0,0}, cL0 = {0,0,0,0}, cL1 = {0,0,0,0};
#pragma unroll
        for (int kt = 0; kt < 4; ++kt) {
            f16x8 ah = *(const f16x8*)&u_hi[l16][kt * 32 + quad * 8];
            f16x8 al = *(const f16x8*)&u_lo[l16][kt * 32 + quad * 8];
            c0  = MFMA16(ah, bch[0][kt], c0);
            c1  = MFMA16(ah, bch[1][kt], c1);
            cL0 = MFMA16(ah, bcl[0][kt], cL0);
            cL1 = MFMA16(ah, bcl[1][kt], cL1);
            cL0 = MFMA16(al, bch[0][kt], cL0);
            cL1 = MFMA16(al, bch[1][kt], cL1);
        }
#pragma unroll
        for (int r = 0; r < 4; ++r) {
            int ndl = quad * 4 + r;
            int go = (base + ndl) * HD;
            float u0 = t1_s[ndl][n0], u1 = t1_s[ndl][n1];
            float r0 = fmaxf(c0[r] + cL0[r] * INV_LOSCALE + vcb0, 0.f);
            float r1 = fmaxf(c1[r] + cL1[r] * INV_LOSCALE + vcb1, 0.f);
            float o0 = u0 + r0, o1 = u1 + r1;
            h[go + n0] = o0; h[go + n1] = o1;
            unsigned short hv, lv;
            split_hl(o0, hv, lv); hhi[go + n0] = hv; hlo[go + n0] = lv;
            split_hl(o1, hv, lv); hhi[go + n1] = hv; hlo[go + n1] = lv;
        }
    }
}

extern "C" void kernel_launch(void* const* d_in, const int* in_sizes, int n_in,
                              void* d_out, int out_size, void* d_ws, size_t ws_size,
                              hipStream_t stream) {
    const float* x    = (const float*)d_in[0];
    const int*   a_ei = (const int*)d_in[1];
    const float* a_ea = (const float*)d_in[2];
    const int*   e_ei = (const int*)d_in[3];
    const float* e_ea = (const float*)d_in[4];
    const float* W_in = (const float*)d_in[5];
    const float* b_in = (const float*)d_in[6];
    const float* aW1  = (const float*)d_in[7];
    const float* ab1  = (const float*)d_in[8];
    const float* aW2  = (const float*)d_in[9];
    const float* ab2  = (const float*)d_in[10];
    const float* eW1  = (const float*)d_in[11];
    const float* eb1  = (const float*)d_in[12];
    const float* eW2  = (const float*)d_in[13];
    const float* eb2  = (const float*)d_in[14];
    const float* ln_g = (const float*)d_in[15];
    const float* ln_b = (const float*)d_in[16];
    const float* cW   = (const float*)d_in[17];
    const float* cb   = (const float*)d_in[18];
    float* h = (float*)d_out;

    // ---- workspace layout, total ~226 MB ----
    char* ws = (char*)d_ws;
    int4* es = (int4*)ws;                        ws += (size_t)2 * EE * 16;     // 19.2 MB
    unsigned short* hhi = (unsigned short*)ws;   ws += (size_t)NN * HD * 2;     // 25.6 MB
    unsigned short* hlo = (unsigned short*)ws;   ws += (size_t)NN * HD * 2;     // 25.6 MB
    float* zagg_a = (float*)ws;                  ws += (size_t)NN * HD * 4;     // 51.2 MB
    float* zagg_e = (float*)ws;                  ws += (size_t)NN * HD * 4;     // 51.2 MB
    float* ctx = (float*)ws;                     ws += (size_t)NN * HD * 4;     // 51.2 MB (shared per graph)
    unsigned short* W1thi = (unsigned short*)ws; ws += (size_t)4 * HD * K1 * 2;
    unsigned short* W1tlo = (unsigned short*)ws; ws += (size_t)4 * HD * K1 * 2;
    unsigned short* W2thi = (unsigned short*)ws; ws += (size_t)2 * HD * 256 * 2;
    unsigned short* W2tlo = (unsigned short*)ws; ws += (size_t)2 * HD * 256 * 2;
    unsigned short* cWthi = (unsigned short*)ws; ws += (size_t)2 * HD * HD * 2;
    unsigned short* cWtlo = (unsigned short*)ws; ws += (size_t)2 * HD * HD * 2;
    float* da = (float*)ws;                      ws += (size_t)NN * 4;
    float* de = (float*)ws;                      ws += (size_t)NN * 4;
    // CSR-build scratch aliased into ctx (dead before first k_ctx writes ctx)
    int* cnt = (int*)ctx;
    int* cur = cnt + 2 * NN;
    int* bsum = cur + 2 * NN;
    int* bpre = bsum + 2 * SCB;

    k_input_proj<<<NN / 16, 256, 0, stream>>>(x, W_in, b_in, h, hhi, hlo);

    // CSR build (once per launch; reused by both layers)
    hipMemsetAsync(cnt, 0, (size_t)2 * NN * 4, stream);
    dim3 ge((EE + 255) / 256, 2);
    k_hist<<<ge, 256, 0, stream>>>(a_ei, e_ei, cnt);
    dim3 gs(SCB, 2);
    k_scanA<<<gs, 256, 0, stream>>>(cnt, bsum);
    k_scanB<<<1, 64, 0, stream>>>(bsum, bpre);
    k_scanC<<<gs, 256, 0, stream>>>(cnt, bpre, cur, da, de);
    k_scatter<<<ge, 256, 0, stream>>>(a_ei, a_ea, e_ei, e_ea, cur, es);

    k_prep_all<<<896, 256, 0, stream>>>(aW1, eW1, aW2, eW2, cW,
                                        W1thi, W1tlo, W2thi, W2tlo, cWthi, cWtlo);

    const int W1SZ = (2 * HD + 2) * HD;
    for (int l = 0; l < 2; ++l) {
        hipMemsetAsync(zagg_a, 0, (size_t)2 * NN * HD * 4, stream);  // zagg_a + zagg_e adjacent
        k_ctx<<<1024, 256, 0, stream>>>(hhi, hlo,
            W1thi + (0 + l) * HD * K1, W1tlo + (0 + l) * HD * K1, ab1 + l * HD, ctx);
        k_edge<<<2048, 256, 0, stream>>>(hhi, hlo, es,
            W1thi + (0 + l) * HD * K1, W1tlo + (0 + l) * HD * K1,
            aW1 + (size_t)l * W1SZ, ctx, zagg_a);
        k_ctx<<<1024, 256, 0, stream>>>(hhi, hlo,
            W1thi + (2 + l) * HD * K1, W1tlo + (2 + l) * HD * K1, eb1 + l * HD, ctx);
        k_edge<<<2048, 256, 0, stream>>>(hhi, hlo, es + (size_t)EE,
            W1thi + (2 + l) * HD * K1, W1tlo + (2 + l) * HD * K1,
            eW1 + (size_t)l * W1SZ, ctx, zagg_e);
        k_node<<<512, 256, 0, stream>>>(h, hhi, hlo, zagg_a, zagg_e, da, de,
            W2thi + l * HD * 256, W2tlo + l * HD * 256, ab2 + l * HD, eb2 + l * HD,
            ln_g + l * HD, ln_b + l * HD,
            cWthi + l * HD * HD, cWtlo + l * HD * HD, cb + l * HD);
    }
}